// Round 6
// baseline (507.059 us; speedup 1.0000x reference)
//
#include <hip/hip_runtime.h>
#include <hip/hip_bf16.h>
#include <stdint.h>

typedef unsigned short u16;
typedef unsigned int u32;
typedef unsigned long long u64;
typedef __attribute__((ext_vector_type(8))) unsigned short u16x8;
typedef __attribute__((ext_vector_type(8))) short short8;
typedef __attribute__((ext_vector_type(4))) float f32x4;

#define CB   4
#define CC   256
#define CHW  4096
#define CNQ  4097
#define NQP  150
#define CHID 1024
#define XTROWS 4160   // 4096 img rows + exemplar + 63 zero pad (65 tiles of 64)
#define VROW   4160   // V cols padded to 65 tiles of 64

// ---------------- workspace layout (bytes) ----------------
#define XT_OFF   0ul                                        // bf16 [B][4160][256] swizzled
#define VB_OFF   (XT_OFF  + (size_t)CB*XTROWS*CC*2)         // bf16 [B][256][4160] swizzled
#define ST_OFF   (VB_OFF  + (size_t)CB*CC*VROW*2)           // bf16 [256][256] (S^T)
#define EXE_OFF  (ST_OFF  + 131072ul)                       // f32  [B][256]
#define ZL_OFF   (EXE_OFF + 4096ul)                         // f32  [B][256]  (S·em)
#define HEAT_OFF (ZL_OFF  + 4096ul)                         // f32  [B][4096]
#define QID_OFF  (HEAT_OFF+ 65536ul)                        // int  [B][160]
#define W1T_OFF  (QID_OFF + 2560ul)                         // f32  [257][1024]
#define W2T_OFF  (W1T_OFF + 1052672ul)                      // f32  [1024][257]
#define HB_OFF   (W2T_OFF + 1052672ul)                      // f32  [600][1024]

__device__ __forceinline__ u16 f2b(float f){
  __hip_bfloat16 h = __float2bfloat16(f); u16 r; __builtin_memcpy(&r, &h, 2); return r;
}
__device__ __forceinline__ f32x4 mfma16(u16x8 a, u16x8 b, f32x4 c){
  short8 as, bs; __builtin_memcpy(&as, &a, 16); __builtin_memcpy(&bs, &b, 16);
  return __builtin_amdgcn_mfma_f32_16x16x32_bf16(as, bs, c, 0, 0, 0);
}
__device__ __forceinline__ u16x8 zero8(){
  u16x8 v;
  #pragma unroll
  for (int e = 0; e < 8; e++) v[e] = 0;
  return v;
}
__device__ __forceinline__ u16x8 cvt8(f32x4 a, f32x4 b){
  u16x8 v;
  v[0]=f2b(a[0]); v[1]=f2b(a[1]); v[2]=f2b(a[2]); v[3]=f2b(a[3]);
  v[4]=f2b(b[0]); v[5]=f2b(b[1]); v[6]=f2b(b[2]); v[7]=f2b(b[3]);
  return v;
}

// ---------------- K0: exemplar mean + z = S·em + Xt exemplar/pad rows --------
__global__ void exe_prep_k(const float* __restrict__ exe, const float* __restrict__ S,
                           float* __restrict__ exeF, float* __restrict__ zl,
                           u16* __restrict__ Xt){
  int b = blockIdx.x, t = threadIdx.x;
  __shared__ float em[CC];
  const float* p = exe + (b*CC + t)*49;
  float s = 0.f;
  for (int i = 0; i < 49; i++) s += p[i];
  float m = s / 49.f;
  em[t] = m;
  exeF[b*CC + t] = m;
  u16* xb = Xt + (size_t)b*XTROWS*CC;
  xb[(size_t)CHW*CC + t] = f2b(m);        // exemplar row (row&7==0 -> no swizzle)
  for (int i = 0; i < 63; i++)            // zero pad rows 4097..4159
    xb[(size_t)(CHW + 1 + i)*CC + t] = 0;
  __syncthreads();
  const float* Sr = S + (long)t*CC;
  float z = 0.f;
  for (int d = 0; d < CC; d++) z += Sr[d] * em[d];
  zl[b*CC + t] = z;
}

// ---------------- K0b: generic f32 transpose (R x C) -> (C x R) --------------
__global__ void tpose_k(const float* __restrict__ src, float* __restrict__ dst,
                        int R, int C){
  __shared__ float tile[32][33];
  int c0 = blockIdx.x*32, r0 = blockIdx.y*32;
  int tc = threadIdx.x & 31, tr = threadIdx.x >> 5;   // 8 rows per pass
  for (int i = tr; i < 32; i += 8){
    int r = r0 + i, c = c0 + tc;
    tile[i][tc] = (r < R && c < C) ? src[(long)r*C + c] : 0.f;
  }
  __syncthreads();
  for (int i = tr; i < 32; i += 8){
    int c = c0 + i, r = r0 + tc;
    if (c < C && r < R) dst[(long)c*R + r] = tile[tc][i];
  }
}

// ---------------- K1: 64x64 tiled transpose, f32 src -> bf16 dst -------------
// swz=1 bakes the flash-kernel K-tile XOR swizzle into the byte-group index so
// flash can stage with linear loads/writes (rule: pre-swizzle the source).
__global__ void transpose64_k(const float* __restrict__ src, u16* __restrict__ dst,
                              int srcLd, long srcBatch, int dstLd, long dstBatch,
                              int swz){
  __shared__ u16 tile[64][72];
  int c0 = blockIdx.x*64, m0 = blockIdx.y*64, b = blockIdx.z;
  const float* S = src + (long)b*srcBatch;
  u16* D = dst + (long)b*dstBatch;
  int t = threadIdx.x;
  int r = t >> 2, q = t & 3;
  for (int uu = q; uu < 8; uu += 4){
    const float* p = S + (long)(c0+r)*srcLd + m0 + uu*8;
    f32x4 a0 = *(const f32x4*)p;
    f32x4 a1 = *(const f32x4*)(p + 4);
    *(u16x8*)&tile[r][uu*8] = cvt8(a0, a1);
  }
  __syncthreads();
  for (int uu = q; uu < 8; uu += 4){
    u16x8 v;
    #pragma unroll
    for (int e = 0; e < 8; e++) v[e] = tile[uu*8 + e][r];
    int gidx = (c0 >> 3) + uu;
    if (swz) gidx ^= (r & 7)*4;
    *(u16x8*)(D + (long)(m0+r)*dstLd + gidx*8) = v;
  }
}

// ---------------- K1b: img f32 -> V bf16 [B][256][4160], pre-swizzled --------
__global__ void vconv_k(const float* __restrict__ imgf, const float* __restrict__ exeF,
                        u16* __restrict__ Vb){
  int rc = blockIdx.x;                  // b*256 + c
  int c = rc & 255;
  int t = threadIdx.x;
  const float* srcrow = imgf + (long)rc*CHW;
  u16* drow = Vb + (long)rc*VROW;
  int cx = c & 7;
  for (int grp = t; grp < VROW/8; grp += 256){
    int G = (grp & ~7) | ((grp & 7) ^ cx);
    int col0 = G*8;
    u16x8 v;
    if (col0 + 8 <= CHW){
      f32x4 a0 = *(const f32x4*)(srcrow + col0);
      f32x4 a1 = *(const f32x4*)(srcrow + col0 + 4);
      v = cvt8(a0, a1);
    } else {
      v = zero8();
      if (col0 == CHW) v[0] = f2b(exeF[rc]);
    }
    *(u16x8*)(drow + grp*8) = v;
  }
}

// ---------------- K2: heat: m-dot with precomputed z ------------------------
__global__ void heat2_k(const float* __restrict__ zl, const float* __restrict__ imgf,
                        float* __restrict__ heat, float* __restrict__ out_img){
  int b = blockIdx.y;
  int t = threadIdx.x;
  __shared__ float z[CC];
  z[t] = zl[b*CC + t];
  __syncthreads();
  int m = blockIdx.x*256 + t;
  const float* base = imgf + (long)b*CC*CHW + m;
  float s = 0.f;
  for (int c = 0; c < CC; c++) s += base[(long)c*CHW] * z[c];
  heat[b*CHW + m] = s;
  out_img[(long)b*257*CHW + (long)256*CHW + m] = s;
}

// ---------------- K3: NMS + top-150 (bitonic, value desc / index asc) --------
__global__ __launch_bounds__(1024) void topk_k(const float* __restrict__ heat,
                                               int* __restrict__ qids,
                                               float* __restrict__ qbuf,
                                               float* __restrict__ out_coords){
  int b = blockIdx.x, t = threadIdx.x;
  __shared__ unsigned long long sk[4096];
  const float* hb = heat + (long)b*CHW;
  for (int p = t; p < 4096; p += 1024){
    int i = p >> 6, j = p & 63;
    float h = hb[p];
    bool ismax = false;
    if (i >= 1 && i < 63 && j >= 1 && j < 63){
      ismax = (h >= hb[p+64]) && (h > hb[p-64]) && (h >= hb[p+1]) && (h > hb[p-1]);
    }
    float sup = ismax ? h : (h - 1e9f);
    unsigned u = __float_as_uint(sup);
    u = (u & 0x80000000u) ? ~u : (u | 0x80000000u);
    unsigned long long key = ((unsigned long long)u << 32) | (unsigned)(0xFFFFFFFFu - (unsigned)p);
    sk[p] = ~key;                       // ascending sort of ~key == desired order
  }
  __syncthreads();
  for (int k = 2; k <= 4096; k <<= 1){
    for (int j = k >> 1; j > 0; j >>= 1){
      for (int tt = t; tt < 2048; tt += 1024){
        int i1 = 2*tt - (tt & (j-1));
        int i2 = i1 + j;
        unsigned long long a = sk[i1], c = sk[i2];
        bool up = ((i1 & k) == 0);
        if (up ? (a > c) : (a < c)){ sk[i1] = c; sk[i2] = a; }
      }
      __syncthreads();
    }
  }
  if (t < NQP){
    unsigned long long key = ~sk[t];
    int p = (int)(0xFFFFFFFFu - (unsigned)(key & 0xFFFFFFFFull));
    qids[b*160 + t] = p;
    out_coords[((long)b*NQP + t)*2 + 0] = (float)(p >> 6);
    out_coords[((long)b*NQP + t)*2 + 1] = (float)(p & 63);
    qbuf[((long)b*NQP + t)*257 + 256] = hb[p];
  }
}

// ---------------- K4: MFMA flash attention + output assembly -----------------
// 256 threads = 4 waves = 2 M x 2 N-halves, 32-row m-tile, grid 128x4 = 512
// blocks -> 2 INDEPENDENT blocks/CU (LDS 72.5KB). While one block drains its
// staging barrier the other computes: cross-block latency hiding that the
// 8-wave/144KB version could not get (1 block/CU lockstep). Single-buffered
// LDS + T14 reg staging from bf16 pre-swizzled Xt/Vb (no cvt in loop).
__global__ __launch_bounds__(256, 2) void flash_k(
    const u16* __restrict__ Xt, const u16* __restrict__ St,
    const u16* __restrict__ Vb, const float* __restrict__ imgf,
    const float* __restrict__ maskp, const float* __restrict__ Wv,
    const int* __restrict__ qids,
    float* __restrict__ out_img, float* __restrict__ qbuf){
  // LDS carve:
  //   [0,32768)      kp   u16[64][256] : K tile; Q round-trip; final T; Tsum
  //   [32768,65536)  kt   u16[256][64] : V^T tile
  //   [65536,69632)  p    u16[32][64]  : P tile (per-wave private)
  //   [69632,73728)  maskb u8[4096]    : mask row (aliased as qid list)
  //   [73728,74240)  mlx  f32[2][2][16][2] : (m,l) exchange for merge
  __shared__ __align__(16) char smem[74240];
  u16*   kp = (u16*)smem;
  u16*   kt = (u16*)(smem + 32768);
  u16*   p_tile = (u16*)(smem + 65536);
  unsigned char* maskb = (unsigned char*)(smem + 69632);
  float* mlx = (float*)(smem + 73728);

  int b = blockIdx.y;
  int m0 = blockIdx.x*32;
  int t = threadIdx.x;
  int lane = t & 63, l15 = lane & 15, qd = lane >> 4;
  int w = t >> 6, wm = w & 1, wn = w >> 1;
  f32x4 zero4 = {0.f,0.f,0.f,0.f};

  const u16* xtb = Xt + (size_t)b*XTROWS*CC;
  const u16* vbb = Vb + (size_t)b*CC*VROW;

  // ---- staging thread mapping + regs (bf16, no cvt) ----
  int kq = t & 3, krow = t >> 2;       // K: 4 thr/row, 64 rows
  int vj = t & 7, vc0 = t >> 3;        // V: 8 thr/row-group, rows vc0+32*i
  u16x8 kreg[8], vreg[8];
#define LOADT(n0_) do { \
    const u16* kr_ = xtb + (long)((n0_) + krow)*CC + kq*8; \
    _Pragma("unroll") \
    for (int i_ = 0; i_ < 8; i_++) kreg[i_] = *(const u16x8*)(kr_ + i_*32); \
    _Pragma("unroll") \
    for (int i_ = 0; i_ < 8; i_++) \
      vreg[i_] = *(const u16x8*)(vbb + (long)(vc0 + 32*i_)*VROW + (n0_) + vj*8); \
  } while(0)
#define WRITET() do { \
    _Pragma("unroll") \
    for (int i_ = 0; i_ < 8; i_++) *(u16x8*)&kp[krow*256 + kq*8 + i_*32] = kreg[i_]; \
    _Pragma("unroll") \
    for (int i_ = 0; i_ < 8; i_++) *(u16x8*)&kt[(vc0 + 32*i_)*64 + vj*8] = vreg[i_]; \
  } while(0)

  // issue tile-0 loads immediately (land during Phase 0)
  LOADT(0);

  // ---- stage mask row into LDS as packed u8 (256 thr x 16 px) ----
  {
    const float* mp = maskp + (long)b*CHW + t*16;
    f32x4 a0 = *(const f32x4*)mp;
    f32x4 a1 = *(const f32x4*)(mp + 4);
    f32x4 a2 = *(const f32x4*)(mp + 8);
    f32x4 a3 = *(const f32x4*)(mp + 12);
    u64 p0 = 0, p1 = 0;
    #pragma unroll
    for (int e = 0; e < 4; e++){
      p0 |= (u64)(a0[e] == 1.0f ? 1u : 0u) << (8*e);
      p0 |= (u64)(a1[e] == 1.0f ? 1u : 0u) << (8*(e+4));
      p1 |= (u64)(a2[e] == 1.0f ? 1u : 0u) << (8*e);
      p1 |= (u64)(a3[e] == 1.0f ? 1u : 0u) << (8*(e+4));
    }
    *(u64*)&maskb[t*16]     = p0;
    *(u64*)&maskb[t*16 + 8] = p1;
  }

  // ---- Phase 0: Q[32][256] = Xrows · St^T (Xt group-swizzled: XOR addr) ----
  {
    f32x4 D[8];
    #pragma unroll
    for (int i = 0; i < 8; i++) D[i] = zero4;
    const u16* arow = xtb + (long)(m0 + wm*16 + l15)*CC;
    int rsw = (l15 & 7)*4;
    #pragma unroll
    for (int ks = 0; ks < 8; ks++){
      u16x8 af = *(const u16x8*)(arow + ((ks*4 + qd) ^ rsw)*8);
      #pragma unroll
      for (int ds = 0; ds < 8; ds++){
        int dsg = wn*8 + ds;
        u16x8 bf_ = *(const u16x8*)(St + (long)(dsg*16 + l15)*CC + ks*32 + qd*8);
        D[ds] = mfma16(af, bf_, D[ds]);
      }
    }
    #pragma unroll
    for (int ds = 0; ds < 8; ds++){
      #pragma unroll
      for (int r = 0; r < 4; r++){
        int prow = wm*16 + qd*4 + r;
        int ccol = (wn*8 + ds)*16 + l15;
        kp[prow*256 + ((ccol >> 3) ^ ((prow & 7)*4))*8 + (ccol & 7)] = f2b(D[ds][r]);
      }
    }
  }
  __syncthreads();
  u16x8 afrag[8];
  {
    int arl = wm*16 + l15;
    #pragma unroll
    for (int ks = 0; ks < 8; ks++)
      afrag[ks] = *(const u16x8*)&kp[arl*256 + (((ks*4 + qd)) ^ ((arl & 7)*4))*8];
  }
  int rowAllowed[4];
  float mi[4], li[4];
  #pragma unroll
  for (int r = 0; r < 4; r++){
    int m = m0 + wm*16 + qd*4 + r;
    rowAllowed[r] = maskb[m];
    mi[r] = -1e30f; li[r] = 0.f;
  }
  f32x4 O[16];
  #pragma unroll
  for (int i = 0; i < 16; i++) O[i] = zero4;
  __syncthreads();   // afrag reads done before staging overwrites kp

  WRITET();          // tile 0 into LDS
  __syncthreads();

  for (int nt = 0; nt < 65; nt++){
    int n0 = nt*64;

    // ---- ISSUE next tile's global loads (latency hides under compute) ----
    if (nt < 64) LOADT(n0 + 64);

    // ---- QK^T (this wave's 32-column half) ----
    f32x4 sc[2];
    sc[0] = zero4; sc[1] = zero4;
    __builtin_amdgcn_s_setprio(1);
    #pragma unroll
    for (int ks = 0; ks < 8; ks++){
      #pragma unroll
      for (int ns = 0; ns < 2; ns++){
        int n_l = (wn*2 + ns)*16 + l15;
        u16x8 bfrag = *(const u16x8*)&kp[n_l*256 + (((ks*4 + qd)) ^ ((n_l & 7)*4))*8];
        sc[ns] = mfma16(afrag[ks], bfrag, sc[ns]);
      }
    }
    __builtin_amdgcn_s_setprio(0);

    // ---- mask bias + online softmax (wave-local, own half) ----
    float sEff[2][4];
    #pragma unroll
    for (int ns = 0; ns < 2; ns++){
      int n = n0 + (wn*2 + ns)*16 + l15;
      bool inv = (n >= CNQ);
      bool isEx = (n == CHW);
      int cm = 0;
      if (!inv && !isEx) cm = maskb[n];
      #pragma unroll
      for (int r = 0; r < 4; r++){
        float s = sc[ns][r];
        float se;
        if (inv)        se = -1e30f;
        else if (isEx)  se = s;
        else            se = (rowAllowed[r] & cm) ? s : s - 1e9f;
        sEff[ns][r] = se;
      }
    }
    float al[4], nm[4];
    #pragma unroll
    for (int r = 0; r < 4; r++){
      float tm = fmaxf(sEff[0][r], sEff[1][r]);
      #pragma unroll
      for (int d = 1; d < 16; d <<= 1) tm = fmaxf(tm, __shfl_xor(tm, d, 16));
      float newm = fmaxf(mi[r], tm);
      al[r] = (mi[r] < -1e29f) ? 0.f : __expf(fmaxf(mi[r] - newm, -88.f));
      nm[r] = newm; mi[r] = newm;
    }
    #pragma unroll
    for (int r = 0; r < 4; r++){
      float rs = 0.f;
      int prow = wm*16 + qd*4 + r;
      #pragma unroll
      for (int ns = 0; ns < 2; ns++){
        float p = __expf(fmaxf(sEff[ns][r] - nm[r], -88.f));
        rs += p;
        int ccol = (wn*2 + ns)*16 + l15;
        p_tile[prow*64 + ((ccol >> 3) ^ (prow & 7))*8 + (ccol & 7)] = f2b(p);
      }
      #pragma unroll
      for (int d = 1; d < 16; d <<= 1) rs += __shfl_xor(rs, d, 16);
      li[r] = li[r]*al[r] + rs;
    }
    // P writes/reads are wave-private regions: no barrier, just drain LDS.
    asm volatile("s_waitcnt lgkmcnt(0)" ::: "memory");

    // ---- rescale T, then T += P·Vtile over this wave's 32-column half ----
    #pragma unroll
    for (int ds = 0; ds < 16; ds++){
      #pragma unroll
      for (int r = 0; r < 4; r++) O[ds][r] *= al[r];
    }
    {
      int prow2 = wm*16 + l15;
      u16x8 pf = *(const u16x8*)&p_tile[prow2*64 + (((wn*4 + qd)) ^ (prow2 & 7))*8];
      __builtin_amdgcn_s_setprio(1);
      #pragma unroll
      for (int ds = 0; ds < 16; ds++){
        int c = ds*16 + l15;
        u16x8 vf = *(const u16x8*)&kt[c*64 + (((wn*4 + qd)) ^ (c & 7))*8];
        O[ds] = mfma16(pf, vf, O[ds]);
      }
      __builtin_amdgcn_s_setprio(0);
    }
    __syncthreads();   // (1) all LDS reads of this tile done
    if (nt < 64) WRITET();
    __syncthreads();   // (2) next tile visible
  }

  // ---- merge the two N-halves (flash-decoding in-block merge) ----
  int* qlds = (int*)maskb;            // mask no longer needed
  if (t < NQP) qlds[t] = qids[b*160 + t];
  if (l15 == 0){
    #pragma unroll
    for (int r = 0; r < 4; r++){
      mlx[(((wm*2 + wn)*16) + qd*4 + r)*2 + 0] = mi[r];
      mlx[(((wm*2 + wn)*16) + qd*4 + r)*2 + 1] = li[r];
    }
  }
  __syncthreads();
  float alpha[4], linv[4];
  #pragma unroll
  for (int r = 0; r < 4; r++){
    float mo = mlx[(((wm*2 + (1 - wn))*16) + qd*4 + r)*2 + 0];
    float lo = mlx[(((wm*2 + (1 - wn))*16) + qd*4 + r)*2 + 1];
    float ms = fmaxf(mi[r], mo);
    float aS = (mi[r] < -1e29f) ? 0.f : __expf(mi[r] - ms);
    float aO = (mo    < -1e29f) ? 0.f : __expf(mo - ms);
    float ls = li[r]*aS + lo*aO;
    alpha[r] = aS;
    linv[r] = (ls > 0.f) ? (1.0f / ls) : 0.f;
  }
  float* Tsum = (float*)smem;         // 32KB f32 scratch in kp region
  if (wn == 1){
    #pragma unroll
    for (int ds = 0; ds < 16; ds++){
      #pragma unroll
      for (int r = 0; r < 4; r++)
        Tsum[(wm*16 + qd*4 + r)*256 + ds*16 + l15] = O[ds][r]*alpha[r];
    }
  }
  __syncthreads();
  if (wn == 0){
    #pragma unroll
    for (int ds = 0; ds < 16; ds++){
      #pragma unroll
      for (int r = 0; r < 4; r++)
        O[ds][r] = (O[ds][r]*alpha[r] + Tsum[(wm*16 + qd*4 + r)*256 + ds*16 + l15]) * linv[r];
    }
  }
  __syncthreads();                    // Tsum reads done before bf16 overwrite
  if (wn == 0){
    #pragma unroll
    for (int ds = 0; ds < 16; ds++){
      #pragma unroll
      for (int r = 0; r < 4; r++){
        int prow = wm*16 + qd*4 + r;
        int ccol = ds*16 + l15;
        kp[prow*256 + ((ccol >> 3) ^ ((prow & 7)*4))*8 + (ccol & 7)] = f2b(O[ds][r]);
      }
    }
  }
  __syncthreads();
  u16x8 tfrag[8];
  {
    int arl = wm*16 + l15;
    #pragma unroll
    for (int ks = 0; ks < 8; ks++)
      tfrag[ks] = *(const u16x8*)&kp[arl*256 + (((ks*4 + qd)) ^ ((arl & 7)*4))*8];
  }
  // ---- final projection F = T_norm · Wv^T, ds split between halves ----
  f32x4 F[8];
  #pragma unroll
  for (int i = 0; i < 8; i++) F[i] = zero4;
  #pragma unroll
  for (int ks = 0; ks < 8; ks++){
    #pragma unroll
    for (int ds = 0; ds < 8; ds++){
      int dsg = wn*8 + ds;
      const float* wr = Wv + (long)(dsg*16 + l15)*CC + ks*32 + qd*8;
      f32x4 w0 = *(const f32x4*)wr;
      f32x4 w1 = *(const f32x4*)(wr + 4);
      F[ds] = mfma16(tfrag[ks], cvt8(w0, w1), F[ds]);
    }
  }

  // ---- epilogue: f32 img_out + f32 query rows (ds-half per wave) ----
  int qix[4];
  #pragma unroll
  for (int r = 0; r < 4; r++){
    int m = m0 + wm*16 + qd*4 + r;
    int f = -1;
    for (int i = 0; i < NQP; i++) if (qlds[i] == m){ f = i; break; }
    qix[r] = f;
  }
  float* oi = out_img + (long)b*257*CHW;
  const float* fi = imgf + (long)b*CC*CHW;
  int mb = m0 + wm*16 + qd*4;
  #pragma unroll
  for (int ds = 0; ds < 8; ds++){
    int d = (wn*8 + ds)*16 + l15;
    f32x4 ivals = *(const f32x4*)(fi + (long)d*CHW + mb);
    f32x4 ovals;
    #pragma unroll
    for (int r = 0; r < 4; r++){
      float v = F[ds][r] + ivals[r];
      ovals[r] = v;
      if (qix[r] >= 0) qbuf[((long)b*NQP + qix[r])*257 + d] = v;
    }
    *(f32x4*)(oi + (long)d*CHW + mb) = ovals;
  }
#undef LOADT
#undef WRITET
}

// ---------------- K5a: LN + layer1 chunk (broadcast GEMV, coalesced W1t) -----
__global__ __launch_bounds__(256) void qhead1_k(const float* __restrict__ qbuf,
    const float* __restrict__ g, const float* __restrict__ be,
    const float* __restrict__ W1t, const float* __restrict__ b1,
    float* __restrict__ Hb){
  int hc = blockIdx.x, rb = blockIdx.y;
  int t = threadIdx.x, lane = t & 63, wv = t >> 6;
  __shared__ __align__(16) float xl[4][260];
  // ---- LN: wave wv normalizes row rb*4+wv (redundant across h-chunks) ----
  {
    const float* row = qbuf + (long)(rb*4 + wv)*257;
    float v[4];
    #pragma unroll
    for (int j = 0; j < 4; j++) v[j] = row[lane + j*64];
    float v4 = (lane == 0) ? row[256] : 0.f;
    float s = v[0]+v[1]+v[2]+v[3]+v4;
    #pragma unroll
    for (int d = 1; d < 64; d <<= 1) s += __shfl_xor(s, d, 64);
    float mu = s / 257.f;
    float d4 = (lane == 0) ? (v4 - mu) : 0.f;
    float vs = d4*d4;
    #pragma unroll
    for (int j = 0; j < 4; j++){ float dd = v[j]-mu; vs += dd*dd; }
    #pragma unroll
    for (int d = 1; d < 64; d <<= 1) vs += __shfl_xor(vs, d, 64);
    float inv = 1.0f / sqrtf(vs/257.f + 1e-5f);
    #pragma unroll
    for (int j = 0; j < 4; j++)
      xl[wv][lane + j*64] = (v[j]-mu)*inv*g[lane + j*64] + be[lane + j*64];
    if (lane == 0) xl[wv][256] = d4*inv*g[256] + be[256];
  }
  __syncthreads();
  int h = hc*256 + t;
  float acc0=0.f, acc1=0.f, acc2=0.f, acc3=0.f;
  #pragma unroll 8
  for (int c = 0; c < 256; c++){
    float wv_ = W1t[(long)c*CHID + h];
    acc0 += wv_*xl[0][c]; acc1 += wv_*xl[1][c];
    acc2 += wv_*xl[2][c]; acc3 += wv_*xl[3][c];
  }
  {
    float wv_ = W1t[(long)256*CHID + h];
    acc0 += wv_*xl[0][256]; acc1 += wv_*xl[1][256];
    acc2 += wv_*xl[2][256]; acc3 += wv_*xl[3][256];
  }
  float bb = b1[h];
  float* hb = Hb + (long)rb*4*CHID + h;
  hb[0]       = fmaxf(acc0 + bb, 0.f);
  hb[CHID]    = fmaxf(acc1 + bb, 0.f);
  hb[2*CHID]  = fmaxf(acc2 + bb, 0.f);
  hb[3*CHID]  = fmaxf(acc3 + bb, 0.f);
}

// ---------------- K5b: layer2 (broadcast GEMV, coalesced W2t) ----------------
__global__ __launch_bounds__(256) void qhead2_k(float* __restrict__ qbuf,
    const float* __restrict__ Hb, const float* __restrict__ W2t,
    const float* __restrict__ b2){
  int rb = blockIdx.x;
  int t = threadIdx.x, lane = t & 63, wv = t >> 6;
  __shared__ __align__(16) float hl[4][CHID];
  const float* hs = Hb + (long)rb*4*CHID;
  #pragma unroll
  for (int q = 0; q < 4; q++)
    *(f32x4*)&hl[q][t*4] = *(const f32x4*)&hs[(long)q*CHID + t*4];
  __syncthreads();
  float a0=0.f, a1=0.f, a2=0.f, a3=0.f;
  #pragma unroll 8
  for (int c = 0; c < CHID; c++){
    float wv_ = W2t[(long)c*257 + t];
    a0 += wv_*hl[0][c]; a1 += wv_*hl[1][c];
    a2 += wv_*hl[2][c]; a3 += wv_*hl[3][c];
  }
  float bb = b2[t];
  qbuf[(long)(rb*4 + 0)*257 + t] = a0 + bb;
  qbuf[(long)(rb*4 + 1)*257 + t] = a1 + bb;
  qbuf[(long)(rb*4 + 2)*257 + t] = a2 + bb;
  qbuf[(long)(rb*4 + 3)*257 + t] = a3 + bb;
  // ---- o = 256 handled by wave 0: 16 c's per lane, shuffle reduce ----
  if (wv == 0){
    float p0=0.f, p1=0.f, p2=0.f, p3=0.f;
    #pragma unroll
    for (int k = 0; k < 16; k++){
      int c = lane*16 + k;
      float wv_ = W2t[(long)c*257 + 256];
      p0 += wv_*hl[0][c]; p1 += wv_*hl[1][c];
      p2 += wv_*hl[2][c]; p3 += wv_*hl[3][c];
    }
    #pragma unroll
    for (int d = 1; d < 64; d <<= 1){
      p0 += __shfl_xor(p0, d, 64); p1 += __shfl_xor(p1, d, 64);
      p2 += __shfl_xor(p2, d, 64); p3 += __shfl_xor(p3, d, 64);
    }
    if (lane == 0){
      float b256 = b2[256];
      qbuf[(long)(rb*4 + 0)*257 + 256] = p0 + b256;
      qbuf[(long)(rb*4 + 1)*257 + 256] = p1 + b256;
      qbuf[(long)(rb*4 + 2)*257 + 256] = p2 + b256;
      qbuf[(long)(rb*4 + 3)*257 + 256] = p3 + b256;
    }
  }
}

// ---------------- launch: input mapping by SIZE (robust to ordering) ---------
extern "C" void kernel_launch(void* const* d_in, const int* in_sizes, int n_in,
                              void* d_out, int out_size, void* d_ws, size_t ws_size,
                              hipStream_t stream){
  (void)out_size; (void)ws_size;
  int idxImg=-1, idxExe=-1, idxMask=-1, idxB1=-1;
  int idx65[2]={-1,-1}; int n65=0;
  int idx263[2]={-1,-1}; int n263=0;
  int idx257[3]={-1,-1,-1}; int n257=0;
  for (int i = 0; i < n_in; i++){
    int s = in_sizes[i];
    if      (s == 4194304) idxImg = i;
    else if (s == 50176)   idxExe = i;
    else if (s == 16384)   idxMask = i;
    else if (s == 1024)    idxB1 = i;
    else if (s == 65536)  { if (n65 < 2)  idx65[n65++] = i; }
    else if (s == 263168) { if (n263 < 2) idx263[n263++] = i; }
    else if (s == 257)    { if (n257 < 3) idx257[n257++] = i; }
  }
  const float* img  = (const float*)d_in[idxImg];
  const float* exe  = (const float*)d_in[idxExe];
  const float* mask = (const float*)d_in[idxMask];
  const float* S    = (const float*)d_in[idx65[0]];   // S before Wv in both dict & sorted order
  const float* Wv   = (const float*)d_in[idx65[1]];
  const float* W1   = (const float*)d_in[idx263[0]];  // W1 before W2 in both orders
  const float* W2   = (const float*)d_in[idx263[1]];
  const float* b1   = (const float*)d_in[idxB1];
  const float *lng, *lnb, *b2;
  if (idxImg == 0){           // dict order: ln_g, ln_b, b2
    lng = (const float*)d_in[idx257[0]];
    lnb = (const float*)d_in[idx257[1]];
    b2  = (const float*)d_in[idx257[2]];
  } else {                    // name-sorted: b2, ln_b, ln_g
    b2  = (const float*)d_in[idx257[0]];
    lnb = (const float*)d_in[idx257[1]];
    lng = (const float*)d_in[idx257[2]];
  }

  char* ws = (char*)d_ws;
  u16*   Xt   = (u16*)(ws + XT_OFF);
  u16*   Vb   = (u16*)(ws + VB_OFF);
  u16*   St   = (u16*)(ws + ST_OFF);
  float* exeF = (float*)(ws + EXE_OFF);
  float* zl   = (float*)(ws + ZL_OFF);
  float* heat = (float*)(ws + HEAT_OFF);
  int*   qids = (int*)(ws + QID_OFF);
  float* W1t  = (float*)(ws + W1T_OFF);
  float* W2t  = (float*)(ws + W2T_OFF);
  float* Hb   = (float*)(ws + HB_OFF);

  float* out      = (float*)d_out;                       // f32 outputs
  float* out_img  = out;                                 // [4][257][4096]
  float* qbuf     = out + (size_t)CB*257*CHW;            // [4][150][257]
  float* out_crd  = qbuf + (size_t)CB*NQP*257;           // [4][150][2]

  exe_prep_k<<<dim3(CB), dim3(256), 0, stream>>>(exe, S, exeF, zl, Xt);
  tpose_k<<<dim3(9, 32), dim3(256), 0, stream>>>(W1, W1t, CHID, 257);
  tpose_k<<<dim3(32, 9), dim3(256), 0, stream>>>(W2, W2t, 257, CHID);
  transpose64_k<<<dim3(4, 64, CB), dim3(256), 0, stream>>>(
      img, Xt, CHW, (long)CC*CHW, CC, (long)XTROWS*CC, 1);
  transpose64_k<<<dim3(4, 4, 1), dim3(256), 0, stream>>>(
      S, St, CC, 0, CC, 0, 0);
  vconv_k<<<dim3(CB*CC), dim3(256), 0, stream>>>(img, exeF, Vb);
  heat2_k<<<dim3(16, CB), dim3(256), 0, stream>>>(zl, img, heat, out_img);
  topk_k<<<dim3(CB), dim3(1024), 0, stream>>>(heat, qids, qbuf, out_crd);
  flash_k<<<dim3(128, CB), dim3(256), 0, stream>>>(
      Xt, St, Vb, img, mask, Wv, qids, out_img, qbuf);
  qhead1_k<<<dim3(4, CB*NQP/4), dim3(256), 0, stream>>>(
      qbuf, lng, lnb, W1t, b1, Hb);
  qhead2_k<<<dim3(CB*NQP/4), dim3(256), 0, stream>>>(qbuf, Hb, W2t, b2);
}

// Round 7
// 461.545 us; speedup vs baseline: 1.0986x; 1.0986x over previous
//
#include <hip/hip_runtime.h>
#include <hip/hip_bf16.h>
#include <stdint.h>

typedef unsigned short u16;
typedef unsigned int u32;
typedef unsigned long long u64;
typedef __attribute__((ext_vector_type(8))) unsigned short u16x8;
typedef __attribute__((ext_vector_type(8))) short short8;
typedef __attribute__((ext_vector_type(4))) float f32x4;

#define CB   4
#define CC   256
#define CHW  4096
#define CNQ  4097
#define NQP  150
#define CHID 1024
#define XTROWS 4160   // 4096 img rows + exemplar + 63 zero pad (65 tiles of 64)
#define VROW   4160   // V cols padded to 65 tiles of 64

// ---------------- workspace layout (bytes) ----------------
#define XT_OFF   0ul                                        // bf16 [B][4160][256] swizzled
#define VB_OFF   (XT_OFF  + (size_t)CB*XTROWS*CC*2)         // bf16 [B][256][4160] swizzled
#define ST_OFF   (VB_OFF  + (size_t)CB*CC*VROW*2)           // bf16 [256][256] (S^T)
#define EXE_OFF  (ST_OFF  + 131072ul)                       // f32  [B][256]
#define ZL_OFF   (EXE_OFF + 4096ul)                         // f32  [B][256]  (S·em)
#define HEAT_OFF (ZL_OFF  + 4096ul)                         // f32  [B][4096]
#define QID_OFF  (HEAT_OFF+ 65536ul)                        // int  [B][160]
#define W1T_OFF  (QID_OFF + 2560ul)                         // f32  [257][1024]
#define W2T_OFF  (W1T_OFF + 1052672ul)                      // f32  [1024][257]
#define HB_OFF   (W2T_OFF + 1052672ul)                      // f32  [600][1024]

__device__ __forceinline__ u16 f2b(float f){
  __hip_bfloat16 h = __float2bfloat16(f); u16 r; __builtin_memcpy(&r, &h, 2); return r;
}
__device__ __forceinline__ f32x4 mfma16(u16x8 a, u16x8 b, f32x4 c){
  short8 as, bs; __builtin_memcpy(&as, &a, 16); __builtin_memcpy(&bs, &b, 16);
  return __builtin_amdgcn_mfma_f32_16x16x32_bf16(as, bs, c, 0, 0, 0);
}
__device__ __forceinline__ u16x8 zero8(){
  u16x8 v;
  #pragma unroll
  for (int e = 0; e < 8; e++) v[e] = 0;
  return v;
}
__device__ __forceinline__ u16x8 cvt8(f32x4 a, f32x4 b){
  u16x8 v;
  v[0]=f2b(a[0]); v[1]=f2b(a[1]); v[2]=f2b(a[2]); v[3]=f2b(a[3]);
  v[4]=f2b(b[0]); v[5]=f2b(b[1]); v[6]=f2b(b[2]); v[7]=f2b(b[3]);
  return v;
}
// async global->LDS, 16B per lane; LDS dest = wave-uniform base + lane*16
__device__ __forceinline__ void glds16(const u16* gp, u16* lp){
  __builtin_amdgcn_global_load_lds(
      (const __attribute__((address_space(1))) u32*)gp,
      (__attribute__((address_space(3))) u32*)lp, 16, 0, 0);
}

// ---------------- shared helper bodies (block-uniform branch safe) -----------
__device__ __forceinline__ void tpose_body(const float* __restrict__ src,
    float* __restrict__ dst, int R, int C, int bx, int by, char* sbuf){
  float (*tile)[33] = (float(*)[33])sbuf;
  int c0 = bx*32, r0 = by*32;
  int tc = threadIdx.x & 31, tr = threadIdx.x >> 5;   // 8 rows per pass
  for (int i = tr; i < 32; i += 8){
    int r = r0 + i, c = c0 + tc;
    tile[i][tc] = (r < R && c < C) ? src[(long)r*C + c] : 0.f;
  }
  __syncthreads();
  for (int i = tr; i < 32; i += 8){
    int c = c0 + i, r = r0 + tc;
    if (c < C && r < R) dst[(long)c*R + r] = tile[tc][i];
  }
}

// 64x64 tiled transpose, f32 src -> bf16 dst; swz=1 bakes flash's K XOR swizzle
__device__ __forceinline__ void t64_body(const float* __restrict__ src,
    u16* __restrict__ dst, int srcLd, long srcBatch, int dstLd, long dstBatch,
    int swz, int bx, int by, int bz, char* sbuf){
  u16 (*tile)[72] = (u16(*)[72])sbuf;
  int c0 = bx*64, m0 = by*64;
  const float* S = src + (long)bz*srcBatch;
  u16* D = dst + (long)bz*dstBatch;
  int t = threadIdx.x;
  int r = t >> 2, q = t & 3;
  for (int uu = q; uu < 8; uu += 4){
    const float* p = S + (long)(c0+r)*srcLd + m0 + uu*8;
    f32x4 a0 = *(const f32x4*)p;
    f32x4 a1 = *(const f32x4*)(p + 4);
    *(u16x8*)&tile[r][uu*8] = cvt8(a0, a1);
  }
  __syncthreads();
  for (int uu = q; uu < 8; uu += 4){
    u16x8 v;
    #pragma unroll
    for (int e = 0; e < 8; e++) v[e] = tile[uu*8 + e][r];
    int gidx = (c0 >> 3) + uu;
    if (swz) gidx ^= (r & 7)*4;
    *(u16x8*)(D + (long)(m0+r)*dstLd + gidx*8) = v;
  }
}

// ---------------- K0 (merged): exe-prep + W1t/W2t transposes + St ------------
// blocks: [0,4) exe_prep | [4,292) W1 tpose | [292,580) W2 tpose | [580,596) St
__global__ __launch_bounds__(256) void prep_k(
    const float* __restrict__ exe, const float* __restrict__ S,
    const float* __restrict__ W1, const float* __restrict__ W2,
    float* __restrict__ exeF, float* __restrict__ zl, u16* __restrict__ Xt,
    u16* __restrict__ St, float* __restrict__ W1t, float* __restrict__ W2t){
  __shared__ __align__(16) char sbuf[9216];
  int id = blockIdx.x, t = threadIdx.x;
  if (id < 4){
    float* em = (float*)sbuf;
    int b = id;
    const float* p = exe + (b*CC + t)*49;
    float s = 0.f;
    for (int i = 0; i < 49; i++) s += p[i];
    float m = s / 49.f;
    em[t] = m;
    exeF[b*CC + t] = m;
    u16* xb = Xt + (size_t)b*XTROWS*CC;
    xb[(size_t)CHW*CC + t] = f2b(m);        // exemplar row (row&7==0: no swizzle)
    for (int i = 0; i < 63; i++)            // zero pad rows 4097..4159
      xb[(size_t)(CHW + 1 + i)*CC + t] = 0;
    __syncthreads();
    const float* Sr = S + (long)t*CC;
    float z = 0.f;
    for (int d = 0; d < CC; d++) z += Sr[d] * em[d];
    zl[b*CC + t] = z;
  } else if (id < 292){
    int i = id - 4;
    tpose_body(W1, W1t, CHID, 257, i % 9, i / 9, sbuf);
  } else if (id < 580){
    int i = id - 292;
    tpose_body(W2, W2t, 257, CHID, i % 32, i / 32, sbuf);
  } else {
    int i = id - 580;
    t64_body(S, St, CC, 0, CC, 0, 0, i & 3, i >> 2, 0, sbuf);
  }
}

// ---------------- K1 (merged): img->Xt transpose + vconv + heat2 -------------
// blocks: [0,1024) t64 img | [1024,2048) vconv | [2048,2112) heat2
__global__ __launch_bounds__(256) void big_k(
    const float* __restrict__ img, const float* __restrict__ exeF,
    const float* __restrict__ zl, u16* __restrict__ Xt, u16* __restrict__ Vb,
    float* __restrict__ heat, float* __restrict__ out_img){
  __shared__ __align__(16) char sbuf[9216];
  int id = blockIdx.x, t = threadIdx.x;
  if (id < 1024){
    int bx = id & 3, by = (id >> 2) & 63, bz = id >> 8;
    t64_body(img, Xt, CHW, (long)CC*CHW, CC, (long)XTROWS*CC, 1, bx, by, bz, sbuf);
  } else if (id < 2048){
    int rc = id - 1024;                  // b*256 + c
    int c = rc & 255;
    const float* srcrow = img + (long)rc*CHW;
    u16* drow = Vb + (long)rc*VROW;
    int cx = c & 7;
    for (int grp = t; grp < VROW/8; grp += 256){
      int G = (grp & ~7) | ((grp & 7) ^ cx);
      int col0 = G*8;
      u16x8 v;
      if (col0 + 8 <= CHW){
        f32x4 a0 = *(const f32x4*)(srcrow + col0);
        f32x4 a1 = *(const f32x4*)(srcrow + col0 + 4);
        v = cvt8(a0, a1);
      } else {
        v = zero8();
        if (col0 == CHW) v[0] = f2b(exeF[rc]);
      }
      *(u16x8*)(drow + grp*8) = v;
    }
  } else {
    int i = id - 2048;
    int bx = i & 15, b = i >> 4;
    float* z = (float*)sbuf;
    z[t] = zl[b*CC + t];
    __syncthreads();
    int m = bx*256 + t;
    const float* base = img + (long)b*CC*CHW + m;
    float s = 0.f;
    for (int c = 0; c < CC; c++) s += base[(long)c*CHW] * z[c];
    heat[b*CHW + m] = s;
    out_img[(long)b*257*CHW + (long)256*CHW + m] = s;
  }
}

// ---------------- K3: NMS + top-150 (bitonic, value desc / index asc) --------
__global__ __launch_bounds__(1024) void topk_k(const float* __restrict__ heat,
                                               int* __restrict__ qids,
                                               float* __restrict__ qbuf,
                                               float* __restrict__ out_coords){
  int b = blockIdx.x, t = threadIdx.x;
  __shared__ unsigned long long sk[4096];
  const float* hb = heat + (long)b*CHW;
  for (int p = t; p < 4096; p += 1024){
    int i = p >> 6, j = p & 63;
    float h = hb[p];
    bool ismax = false;
    if (i >= 1 && i < 63 && j >= 1 && j < 63){
      ismax = (h >= hb[p+64]) && (h > hb[p-64]) && (h >= hb[p+1]) && (h > hb[p-1]);
    }
    float sup = ismax ? h : (h - 1e9f);
    unsigned u = __float_as_uint(sup);
    u = (u & 0x80000000u) ? ~u : (u | 0x80000000u);
    unsigned long long key = ((unsigned long long)u << 32) | (unsigned)(0xFFFFFFFFu - (unsigned)p);
    sk[p] = ~key;                       // ascending sort of ~key == desired order
  }
  __syncthreads();
  for (int k = 2; k <= 4096; k <<= 1){
    for (int j = k >> 1; j > 0; j >>= 1){
      for (int tt = t; tt < 2048; tt += 1024){
        int i1 = 2*tt - (tt & (j-1));
        int i2 = i1 + j;
        unsigned long long a = sk[i1], c = sk[i2];
        bool up = ((i1 & k) == 0);
        if (up ? (a > c) : (a < c)){ sk[i1] = c; sk[i2] = a; }
      }
      __syncthreads();
    }
  }
  if (t < NQP){
    unsigned long long key = ~sk[t];
    int p = (int)(0xFFFFFFFFu - (unsigned)(key & 0xFFFFFFFFull));
    qids[b*160 + t] = p;
    out_coords[((long)b*NQP + t)*2 + 0] = (float)(p >> 6);
    out_coords[((long)b*NQP + t)*2 + 1] = (float)(p & 63);
    qbuf[((long)b*NQP + t)*257 + 256] = hb[p];
  }
}

// ---------------- K4: MFMA flash attention + output assembly -----------------
// 256 threads = 4 waves = 2 M x 2 N-halves, 32-row m-tile, grid 128x4 = 512
// blocks -> 2 INDEPENDENT blocks/CU (LDS 74,240B x2 = 148KB < 160KB). Staging
// via global_load_lds (lane-linear, conflict-free — R6's manual ds_write was a
// 16-way write conflict, 17.6M conflicts). Single-buffered: compute -> barrier
// -> issue glds -> barrier(drain); drain hides under the other block's compute.
__global__ __launch_bounds__(256, 2) void flash_k(
    const u16* __restrict__ Xt, const u16* __restrict__ St,
    const u16* __restrict__ Vb, const float* __restrict__ imgf,
    const float* __restrict__ maskp, const float* __restrict__ Wv,
    const int* __restrict__ qids,
    float* __restrict__ out_img, float* __restrict__ qbuf){
  // LDS carve:
  //   [0,32768)      kp   u16[64][256] : K tile; Q round-trip; final T; Tsum
  //   [32768,65536)  kt   u16[256][64] : V^T tile
  //   [65536,69632)  p    u16[32][64]  : P tile (per-wave private)
  //   [69632,73728)  maskb u8[4096]    : mask row (aliased as qid list)
  //   [73728,74240)  mlx  f32[2][2][16][2] : (m,l) exchange for merge
  __shared__ __align__(16) char smem[74240];
  u16*   kp = (u16*)smem;
  u16*   kt = (u16*)(smem + 32768);
  u16*   p_tile = (u16*)(smem + 65536);
  unsigned char* maskb = (unsigned char*)(smem + 69632);
  float* mlx = (float*)(smem + 73728);

  int b = blockIdx.y;
  int m0 = blockIdx.x*32;
  int t = threadIdx.x;
  int lane = t & 63, l15 = lane & 15, qd = lane >> 4;
  int w = t >> 6, wm = w & 1, wn = w >> 1;
  f32x4 zero4 = {0.f,0.f,0.f,0.f};

  const u16* xtb = Xt + (size_t)b*XTROWS*CC;
  const u16* vbb = Vb + (size_t)b*CC*VROW;

  // ---- stage mask row into LDS as packed u8 (256 thr x 16 px) ----
  {
    const float* mp = maskp + (long)b*CHW + t*16;
    f32x4 a0 = *(const f32x4*)mp;
    f32x4 a1 = *(const f32x4*)(mp + 4);
    f32x4 a2 = *(const f32x4*)(mp + 8);
    f32x4 a3 = *(const f32x4*)(mp + 12);
    u64 p0 = 0, p1 = 0;
    #pragma unroll
    for (int e = 0; e < 4; e++){
      p0 |= (u64)(a0[e] == 1.0f ? 1u : 0u) << (8*e);
      p0 |= (u64)(a1[e] == 1.0f ? 1u : 0u) << (8*(e+4));
      p1 |= (u64)(a2[e] == 1.0f ? 1u : 0u) << (8*e);
      p1 |= (u64)(a3[e] == 1.0f ? 1u : 0u) << (8*(e+4));
    }
    *(u64*)&maskb[t*16]     = p0;
    *(u64*)&maskb[t*16 + 8] = p1;
  }

  // ---- Phase 0: Q[32][256] = Xrows · St^T (Xt group-swizzled: XOR addr) ----
  {
    f32x4 D[8];
    #pragma unroll
    for (int i = 0; i < 8; i++) D[i] = zero4;
    const u16* arow = xtb + (long)(m0 + wm*16 + l15)*CC;
    int rsw = (l15 & 7)*4;
    #pragma unroll
    for (int ks = 0; ks < 8; ks++){
      u16x8 af = *(const u16x8*)(arow + ((ks*4 + qd) ^ rsw)*8);
      #pragma unroll
      for (int ds = 0; ds < 8; ds++){
        int dsg = wn*8 + ds;
        u16x8 bf_ = *(const u16x8*)(St + (long)(dsg*16 + l15)*CC + ks*32 + qd*8);
        D[ds] = mfma16(af, bf_, D[ds]);
      }
    }
    #pragma unroll
    for (int ds = 0; ds < 8; ds++){
      #pragma unroll
      for (int r = 0; r < 4; r++){
        int prow = wm*16 + qd*4 + r;
        int ccol = (wn*8 + ds)*16 + l15;
        kp[prow*256 + ((ccol >> 3) ^ ((prow & 7)*4))*8 + (ccol & 7)] = f2b(D[ds][r]);
      }
    }
  }
  __syncthreads();
  u16x8 afrag[8];
  {
    int arl = wm*16 + l15;
    #pragma unroll
    for (int ks = 0; ks < 8; ks++)
      afrag[ks] = *(const u16x8*)&kp[arl*256 + (((ks*4 + qd)) ^ ((arl & 7)*4))*8];
  }
  int rowAllowed[4];
  float mi[4], li[4];
  #pragma unroll
  for (int r = 0; r < 4; r++){
    int m = m0 + wm*16 + qd*4 + r;
    rowAllowed[r] = maskb[m];
    mi[r] = -1e30f; li[r] = 0.f;
  }
  f32x4 O[16];
  #pragma unroll
  for (int i = 0; i < 16; i++) O[i] = zero4;
  __syncthreads();   // afrag reads done before staging overwrites kp

  // ---- staging: 16 glds per wave, lane-linear (conflict-free) ----
#define STAGE(n0_) do { \
    const u16* ksrc_ = xtb + (long)(n0_)*CC + w*4096 + lane*8; \
    u16* kl_ = kp + w*4096; \
    _Pragma("unroll") \
    for (int i_ = 0; i_ < 8; i_++) glds16(ksrc_ + i_*512, kl_ + i_*512); \
    const u16* vsrc_ = vbb + (long)(w*64 + (lane >> 3))*VROW + (n0_) + (lane & 7)*8; \
    u16* vl_ = kt + w*4096; \
    _Pragma("unroll") \
    for (int i_ = 0; i_ < 8; i_++) glds16(vsrc_ + (long)i_*8*VROW, vl_ + i_*512); \
  } while(0)

  STAGE(0);
  __syncthreads();   // drains vmcnt -> tile 0 ready

  for (int nt = 0; nt < 65; nt++){
    int n0 = nt*64;

    // ---- QK^T (this wave's 32-column half) ----
    f32x4 sc[2];
    sc[0] = zero4; sc[1] = zero4;
    __builtin_amdgcn_s_setprio(1);
    #pragma unroll
    for (int ks = 0; ks < 8; ks++){
      #pragma unroll
      for (int ns = 0; ns < 2; ns++){
        int n_l = (wn*2 + ns)*16 + l15;
        u16x8 bfrag = *(const u16x8*)&kp[n_l*256 + (((ks*4 + qd)) ^ ((n_l & 7)*4))*8];
        sc[ns] = mfma16(afrag[ks], bfrag, sc[ns]);
      }
    }
    __builtin_amdgcn_s_setprio(0);

    // ---- mask bias + online softmax (wave-local, own half) ----
    float sEff[2][4];
    #pragma unroll
    for (int ns = 0; ns < 2; ns++){
      int n = n0 + (wn*2 + ns)*16 + l15;
      bool inv = (n >= CNQ);
      bool isEx = (n == CHW);
      int cm = 0;
      if (!inv && !isEx) cm = maskb[n];
      #pragma unroll
      for (int r = 0; r < 4; r++){
        float s = sc[ns][r];
        float se;
        if (inv)        se = -1e30f;
        else if (isEx)  se = s;
        else            se = (rowAllowed[r] & cm) ? s : s - 1e9f;
        sEff[ns][r] = se;
      }
    }
    float al[4], nm[4];
    #pragma unroll
    for (int r = 0; r < 4; r++){
      float tm = fmaxf(sEff[0][r], sEff[1][r]);
      #pragma unroll
      for (int d = 1; d < 16; d <<= 1) tm = fmaxf(tm, __shfl_xor(tm, d, 16));
      float newm = fmaxf(mi[r], tm);
      al[r] = (mi[r] < -1e29f) ? 0.f : __expf(fmaxf(mi[r] - newm, -88.f));
      nm[r] = newm; mi[r] = newm;
    }
    #pragma unroll
    for (int r = 0; r < 4; r++){
      float rs = 0.f;
      int prow = wm*16 + qd*4 + r;
      #pragma unroll
      for (int ns = 0; ns < 2; ns++){
        float p = __expf(fmaxf(sEff[ns][r] - nm[r], -88.f));
        rs += p;
        int ccol = (wn*2 + ns)*16 + l15;
        p_tile[prow*64 + ((ccol >> 3) ^ (prow & 7))*8 + (ccol & 7)] = f2b(p);
      }
      #pragma unroll
      for (int d = 1; d < 16; d <<= 1) rs += __shfl_xor(rs, d, 16);
      li[r] = li[r]*al[r] + rs;
    }
    // P writes/reads are wave-private regions: no barrier, just drain LDS.
    asm volatile("s_waitcnt lgkmcnt(0)" ::: "memory");

    // ---- rescale T, then T += P·Vtile over this wave's 32-column half ----
    #pragma unroll
    for (int ds = 0; ds < 16; ds++){
      #pragma unroll
      for (int r = 0; r < 4; r++) O[ds][r] *= al[r];
    }
    {
      int prow2 = wm*16 + l15;
      u16x8 pf = *(const u16x8*)&p_tile[prow2*64 + (((wn*4 + qd)) ^ (prow2 & 7))*8];
      __builtin_amdgcn_s_setprio(1);
      #pragma unroll
      for (int ds = 0; ds < 16; ds++){
        int c = ds*16 + l15;
        u16x8 vf = *(const u16x8*)&kt[c*64 + (((wn*4 + qd)) ^ (c & 7))*8];
        O[ds] = mfma16(pf, vf, O[ds]);
      }
      __builtin_amdgcn_s_setprio(0);
    }
    __syncthreads();   // (1) all LDS reads of this tile done
    if (nt < 64) STAGE(n0 + 64);
    __syncthreads();   // (2) vmcnt drained -> next tile visible
  }
#undef STAGE

  // ---- merge the two N-halves (flash-decoding in-block merge) ----
  int* qlds = (int*)maskb;            // mask no longer needed
  if (t < NQP) qlds[t] = qids[b*160 + t];
  if (l15 == 0){
    #pragma unroll
    for (int r = 0; r < 4; r++){
      mlx[(((wm*2 + wn)*16) + qd*4 + r)*2 + 0] = mi[r];
      mlx[(((wm*2 + wn)*16) + qd*4 + r)*2 + 1] = li[r];
    }
  }
  __syncthreads();
  float alpha[4], linv[4];
  #pragma unroll
  for (int r = 0; r < 4; r++){
    float mo = mlx[(((wm*2 + (1 - wn))*16) + qd*4 + r)*2 + 0];
    float lo = mlx[(((wm*2 + (1 - wn))*16) + qd*4 + r)*2 + 1];
    float ms = fmaxf(mi[r], mo);
    float aS = (mi[r] < -1e29f) ? 0.f : __expf(mi[r] - ms);
    float aO = (mo    < -1e29f) ? 0.f : __expf(mo - ms);
    float ls = li[r]*aS + lo*aO;
    alpha[r] = aS;
    linv[r] = (ls > 0.f) ? (1.0f / ls) : 0.f;
  }
  float* Tsum = (float*)smem;         // 32KB f32 scratch in kp region
  if (wn == 1){
    #pragma unroll
    for (int ds = 0; ds < 16; ds++){
      #pragma unroll
      for (int r = 0; r < 4; r++)
        Tsum[(wm*16 + qd*4 + r)*256 + ds*16 + l15] = O[ds][r]*alpha[r];
    }
  }
  __syncthreads();
  if (wn == 0){
    #pragma unroll
    for (int ds = 0; ds < 16; ds++){
      #pragma unroll
      for (int r = 0; r < 4; r++)
        O[ds][r] = (O[ds][r]*alpha[r] + Tsum[(wm*16 + qd*4 + r)*256 + ds*16 + l15]) * linv[r];
    }
  }
  __syncthreads();                    // Tsum reads done before bf16 overwrite
  if (wn == 0){
    #pragma unroll
    for (int ds = 0; ds < 16; ds++){
      #pragma unroll
      for (int r = 0; r < 4; r++){
        int prow = wm*16 + qd*4 + r;
        int ccol = ds*16 + l15;
        kp[prow*256 + ((ccol >> 3) ^ ((prow & 7)*4))*8 + (ccol & 7)] = f2b(O[ds][r]);
      }
    }
  }
  __syncthreads();
  u16x8 tfrag[8];
  {
    int arl = wm*16 + l15;
    #pragma unroll
    for (int ks = 0; ks < 8; ks++)
      tfrag[ks] = *(const u16x8*)&kp[arl*256 + (((ks*4 + qd)) ^ ((arl & 7)*4))*8];
  }
  // ---- final projection F = T_norm · Wv^T, ds split between halves ----
  f32x4 F[8];
  #pragma unroll
  for (int i = 0; i < 8; i++) F[i] = zero4;
  #pragma unroll
  for (int ks = 0; ks < 8; ks++){
    #pragma unroll
    for (int ds = 0; ds < 8; ds++){
      int dsg = wn*8 + ds;
      const float* wr = Wv + (long)(dsg*16 + l15)*CC + ks*32 + qd*8;
      f32x4 w0 = *(const f32x4*)wr;
      f32x4 w1 = *(const f32x4*)(wr + 4);
      F[ds] = mfma16(tfrag[ks], cvt8(w0, w1), F[ds]);
    }
  }

  // ---- epilogue: f32 img_out + f32 query rows (ds-half per wave) ----
  int qix[4];
  #pragma unroll
  for (int r = 0; r < 4; r++){
    int m = m0 + wm*16 + qd*4 + r;
    int f = -1;
    for (int i = 0; i < NQP; i++) if (qlds[i] == m){ f = i; break; }
    qix[r] = f;
  }
  float* oi = out_img + (long)b*257*CHW;
  const float* fi = imgf + (long)b*CC*CHW;
  int mb = m0 + wm*16 + qd*4;
  #pragma unroll
  for (int ds = 0; ds < 8; ds++){
    int d = (wn*8 + ds)*16 + l15;
    f32x4 ivals = *(const f32x4*)(fi + (long)d*CHW + mb);
    f32x4 ovals;
    #pragma unroll
    for (int r = 0; r < 4; r++){
      float v = F[ds][r] + ivals[r];
      ovals[r] = v;
      if (qix[r] >= 0) qbuf[((long)b*NQP + qix[r])*257 + d] = v;
    }
    *(f32x4*)(oi + (long)d*CHW + mb) = ovals;
  }
}

// ---------------- K5a: LN + layer1 chunk (broadcast GEMV, coalesced W1t) -----
__global__ __launch_bounds__(256) void qhead1_k(const float* __restrict__ qbuf,
    const float* __restrict__ g, const float* __restrict__ be,
    const float* __restrict__ W1t, const float* __restrict__ b1,
    float* __restrict__ Hb){
  int hc = blockIdx.x, rb = blockIdx.y;
  int t = threadIdx.x, lane = t & 63, wv = t >> 6;
  __shared__ __align__(16) float xl[4][260];
  // ---- LN: wave wv normalizes row rb*4+wv (redundant across h-chunks) ----
  {
    const float* row = qbuf + (long)(rb*4 + wv)*257;
    float v[4];
    #pragma unroll
    for (int j = 0; j < 4; j++) v[j] = row[lane + j*64];
    float v4 = (lane == 0) ? row[256] : 0.f;
    float s = v[0]+v[1]+v[2]+v[3]+v4;
    #pragma unroll
    for (int d = 1; d < 64; d <<= 1) s += __shfl_xor(s, d, 64);
    float mu = s / 257.f;
    float d4 = (lane == 0) ? (v4 - mu) : 0.f;
    float vs = d4*d4;
    #pragma unroll
    for (int j = 0; j < 4; j++){ float dd = v[j]-mu; vs += dd*dd; }
    #pragma unroll
    for (int d = 1; d < 64; d <<= 1) vs += __shfl_xor(vs, d, 64);
    float inv = 1.0f / sqrtf(vs/257.f + 1e-5f);
    #pragma unroll
    for (int j = 0; j < 4; j++)
      xl[wv][lane + j*64] = (v[j]-mu)*inv*g[lane + j*64] + be[lane + j*64];
    if (lane == 0) xl[wv][256] = d4*inv*g[256] + be[256];
  }
  __syncthreads();
  int h = hc*256 + t;
  float acc0=0.f, acc1=0.f, acc2=0.f, acc3=0.f;
  #pragma unroll 8
  for (int c = 0; c < 256; c++){
    float wv_ = W1t[(long)c*CHID + h];
    acc0 += wv_*xl[0][c]; acc1 += wv_*xl[1][c];
    acc2 += wv_*xl[2][c]; acc3 += wv_*xl[3][c];
  }
  {
    float wv_ = W1t[(long)256*CHID + h];
    acc0 += wv_*xl[0][256]; acc1 += wv_*xl[1][256];
    acc2 += wv_*xl[2][256]; acc3 += wv_*xl[3][256];
  }
  float bb = b1[h];
  float* hb = Hb + (long)rb*4*CHID + h;
  hb[0]       = fmaxf(acc0 + bb, 0.f);
  hb[CHID]    = fmaxf(acc1 + bb, 0.f);
  hb[2*CHID]  = fmaxf(acc2 + bb, 0.f);
  hb[3*CHID]  = fmaxf(acc3 + bb, 0.f);
}

// ---------------- K5b: layer2 (broadcast GEMV, coalesced W2t) ----------------
__global__ __launch_bounds__(256) void qhead2_k(float* __restrict__ qbuf,
    const float* __restrict__ Hb, const float* __restrict__ W2t,
    const float* __restrict__ b2){
  int rb = blockIdx.x;
  int t = threadIdx.x, lane = t & 63, wv = t >> 6;
  __shared__ __align__(16) float hl[4][CHID];
  const float* hs = Hb + (long)rb*4*CHID;
  #pragma unroll
  for (int q = 0; q < 4; q++)
    *(f32x4*)&hl[q][t*4] = *(const f32x4*)&hs[(long)q*CHID + t*4];
  __syncthreads();
  float a0=0.f, a1=0.f, a2=0.f, a3=0.f;
  #pragma unroll 8
  for (int c = 0; c < CHID; c++){
    float wv_ = W2t[(long)c*257 + t];
    a0 += wv_*hl[0][c]; a1 += wv_*hl[1][c];
    a2 += wv_*hl[2][c]; a3 += wv_*hl[3][c];
  }
  float bb = b2[t];
  qbuf[(long)(rb*4 + 0)*257 + t] = a0 + bb;
  qbuf[(long)(rb*4 + 1)*257 + t] = a1 + bb;
  qbuf[(long)(rb*4 + 2)*257 + t] = a2 + bb;
  qbuf[(long)(rb*4 + 3)*257 + t] = a3 + bb;
  // ---- o = 256 handled by wave 0: 16 c's per lane, shuffle reduce ----
  if (wv == 0){
    float p0=0.f, p1=0.f, p2=0.f, p3=0.f;
    #pragma unroll
    for (int k = 0; k < 16; k++){
      int c = lane*16 + k;
      float wv_ = W2t[(long)c*257 + 256];
      p0 += wv_*hl[0][c]; p1 += wv_*hl[1][c];
      p2 += wv_*hl[2][c]; p3 += wv_*hl[3][c];
    }
    #pragma unroll
    for (int d = 1; d < 64; d <<= 1){
      p0 += __shfl_xor(p0, d, 64); p1 += __shfl_xor(p1, d, 64);
      p2 += __shfl_xor(p2, d, 64); p3 += __shfl_xor(p3, d, 64);
    }
    if (lane == 0){
      float b256 = b2[256];
      qbuf[(long)(rb*4 + 0)*257 + 256] = p0 + b256;
      qbuf[(long)(rb*4 + 1)*257 + 256] = p1 + b256;
      qbuf[(long)(rb*4 + 2)*257 + 256] = p2 + b256;
      qbuf[(long)(rb*4 + 3)*257 + 256] = p3 + b256;
    }
  }
}

// ---------------- launch: input mapping by SIZE (robust to ordering) ---------
extern "C" void kernel_launch(void* const* d_in, const int* in_sizes, int n_in,
                              void* d_out, int out_size, void* d_ws, size_t ws_size,
                              hipStream_t stream){
  (void)out_size; (void)ws_size;
  int idxImg=-1, idxExe=-1, idxMask=-1, idxB1=-1;
  int idx65[2]={-1,-1}; int n65=0;
  int idx263[2]={-1,-1}; int n263=0;
  int idx257[3]={-1,-1,-1}; int n257=0;
  for (int i = 0; i < n_in; i++){
    int s = in_sizes[i];
    if      (s == 4194304) idxImg = i;
    else if (s == 50176)   idxExe = i;
    else if (s == 16384)   idxMask = i;
    else if (s == 1024)    idxB1 = i;
    else if (s == 65536)  { if (n65 < 2)  idx65[n65++] = i; }
    else if (s == 263168) { if (n263 < 2) idx263[n263++] = i; }
    else if (s == 257)    { if (n257 < 3) idx257[n257++] = i; }
  }
  const float* img  = (const float*)d_in[idxImg];
  const float* exe  = (const float*)d_in[idxExe];
  const float* mask = (const float*)d_in[idxMask];
  const float* S    = (const float*)d_in[idx65[0]];   // S before Wv in both dict & sorted order
  const float* Wv   = (const float*)d_in[idx65[1]];
  const float* W1   = (const float*)d_in[idx263[0]];  // W1 before W2 in both orders
  const float* W2   = (const float*)d_in[idx263[1]];
  const float* b1   = (const float*)d_in[idxB1];
  const float *lng, *lnb, *b2;
  if (idxImg == 0){           // dict order: ln_g, ln_b, b2
    lng = (const float*)d_in[idx257[0]];
    lnb = (const float*)d_in[idx257[1]];
    b2  = (const float*)d_in[idx257[2]];
  } else {                    // name-sorted: b2, ln_b, ln_g
    b2  = (const float*)d_in[idx257[0]];
    lnb = (const float*)d_in[idx257[1]];
    lng = (const float*)d_in[idx257[2]];
  }

  char* ws = (char*)d_ws;
  u16*   Xt   = (u16*)(ws + XT_OFF);
  u16*   Vb   = (u16*)(ws + VB_OFF);
  u16*   St   = (u16*)(ws + ST_OFF);
  float* exeF = (float*)(ws + EXE_OFF);
  float* zl   = (float*)(ws + ZL_OFF);
  float* heat = (float*)(ws + HEAT_OFF);
  int*   qids = (int*)(ws + QID_OFF);
  float* W1t  = (float*)(ws + W1T_OFF);
  float* W2t  = (float*)(ws + W2T_OFF);
  float* Hb   = (float*)(ws + HB_OFF);

  float* out      = (float*)d_out;                       // f32 outputs
  float* out_img  = out;                                 // [4][257][4096]
  float* qbuf     = out + (size_t)CB*257*CHW;            // [4][150][257]
  float* out_crd  = qbuf + (size_t)CB*NQP*257;           // [4][150][2]

  prep_k<<<dim3(596), dim3(256), 0, stream>>>(
      exe, S, W1, W2, exeF, zl, Xt, St, W1t, W2t);
  big_k<<<dim3(2112), dim3(256), 0, stream>>>(
      img, exeF, zl, Xt, Vb, heat, out_img);
  topk_k<<<dim3(CB), dim3(1024), 0, stream>>>(heat, qids, qbuf, out_crd);
  flash_k<<<dim3(128, CB), dim3(256), 0, stream>>>(
      Xt, St, Vb, img, mask, Wv, qids, out_img, qbuf);
  qhead1_k<<<dim3(4, CB*NQP/4), dim3(256), 0, stream>>>(
      qbuf, lng, lnb, W1t, b1, Hb);
  qhead2_k<<<dim3(CB*NQP/4), dim3(256), 0, stream>>>(qbuf, Hb, W2t, b2);
}

// Round 8
// 425.658 us; speedup vs baseline: 1.1912x; 1.0843x over previous
//
#include <hip/hip_runtime.h>
#include <hip/hip_bf16.h>
#include <stdint.h>

typedef unsigned short u16;
typedef unsigned int u32;
typedef unsigned long long u64;
typedef __attribute__((ext_vector_type(8))) unsigned short u16x8;
typedef __attribute__((ext_vector_type(8))) short short8;
typedef __attribute__((ext_vector_type(4))) float f32x4;

#define CB   4
#define CC   256
#define CHW  4096
#define CNQ  4097
#define NQP  150
#define CHID 1024
#define XTROWS 4160   // 4096 img rows + exemplar + 63 zero pad (65 tiles of 64)
#define VROW   4160   // V cols padded to 65 tiles of 64

// ---------------- workspace layout (bytes) ----------------
#define XT_OFF   0ul                                        // bf16 [B][4160][256] swizzled
#define VB_OFF   (XT_OFF  + (size_t)CB*XTROWS*CC*2)         // bf16 [B][256][4160] swizzled
#define ST_OFF   (VB_OFF  + (size_t)CB*CC*VROW*2)           // bf16 [256][256] (S^T)
#define EXE_OFF  (ST_OFF  + 131072ul)                       // f32  [B][256]
#define ZL_OFF   (EXE_OFF + 4096ul)                         // f32  [B][256]  (S·em)
#define HEAT_OFF (ZL_OFF  + 4096ul)                         // f32  [B][4096]
#define QID_OFF  (HEAT_OFF+ 65536ul)                        // int  [B][160]
#define W1T_OFF  (QID_OFF + 2560ul)                         // f32  [257][1024]
#define W2T_OFF  (W1T_OFF + 1052672ul)                      // f32  [1024][257]
#define HB_OFF   (W2T_OFF + 1052672ul)                      // f32  [600][1024]

__device__ __forceinline__ u16 f2b(float f){
  __hip_bfloat16 h = __float2bfloat16(f); u16 r; __builtin_memcpy(&r, &h, 2); return r;
}
__device__ __forceinline__ f32x4 mfma16(u16x8 a, u16x8 b, f32x4 c){
  short8 as, bs; __builtin_memcpy(&as, &a, 16); __builtin_memcpy(&bs, &b, 16);
  return __builtin_amdgcn_mfma_f32_16x16x32_bf16(as, bs, c, 0, 0, 0);
}
__device__ __forceinline__ u16x8 zero8(){
  u16x8 v;
  #pragma unroll
  for (int e = 0; e < 8; e++) v[e] = 0;
  return v;
}
__device__ __forceinline__ u16x8 cvt8(f32x4 a, f32x4 b){
  u16x8 v;
  v[0]=f2b(a[0]); v[1]=f2b(a[1]); v[2]=f2b(a[2]); v[3]=f2b(a[3]);
  v[4]=f2b(b[0]); v[5]=f2b(b[1]); v[6]=f2b(b[2]); v[7]=f2b(b[3]);
  return v;
}
// async global->LDS, 16B per lane; LDS dest = wave-uniform base + lane*16
__device__ __forceinline__ void glds16(const u16* gp, u16* lp){
  __builtin_amdgcn_global_load_lds(
      (const __attribute__((address_space(1))) u32*)gp,
      (__attribute__((address_space(3))) u32*)lp, 16, 0, 0);
}

// ---------------- shared helper bodies (block-uniform branch safe) -----------
__device__ __forceinline__ void tpose_body(const float* __restrict__ src,
    float* __restrict__ dst, int R, int C, int bx, int by, char* sbuf){
  float (*tile)[33] = (float(*)[33])sbuf;
  int c0 = bx*32, r0 = by*32;
  int tc = threadIdx.x & 31, tr = threadIdx.x >> 5;   // 8 rows per pass
  for (int i = tr; i < 32; i += 8){
    int r = r0 + i, c = c0 + tc;
    tile[i][tc] = (r < R && c < C) ? src[(long)r*C + c] : 0.f;
  }
  __syncthreads();
  for (int i = tr; i < 32; i += 8){
    int c = c0 + i, r = r0 + tc;
    if (c < C && r < R) dst[(long)c*R + r] = tile[tc][i];
  }
}

// 64x64 tiled transpose, f32 src -> bf16 dst; swz=1 bakes flash's K XOR swizzle
__device__ __forceinline__ void t64_body(const float* __restrict__ src,
    u16* __restrict__ dst, int srcLd, long srcBatch, int dstLd, long dstBatch,
    int swz, int bx, int by, int bz, char* sbuf){
  u16 (*tile)[72] = (u16(*)[72])sbuf;
  int c0 = bx*64, m0 = by*64;
  const float* S = src + (long)bz*srcBatch;
  u16* D = dst + (long)bz*dstBatch;
  int t = threadIdx.x;
  int r = t >> 2, q = t & 3;
  for (int uu = q; uu < 8; uu += 4){
    const float* p = S + (long)(c0+r)*srcLd + m0 + uu*8;
    f32x4 a0 = *(const f32x4*)p;
    f32x4 a1 = *(const f32x4*)(p + 4);
    *(u16x8*)&tile[r][uu*8] = cvt8(a0, a1);
  }
  __syncthreads();
  for (int uu = q; uu < 8; uu += 4){
    u16x8 v;
    #pragma unroll
    for (int e = 0; e < 8; e++) v[e] = tile[uu*8 + e][r];
    int gidx = (c0 >> 3) + uu;
    if (swz) gidx ^= (r & 7)*4;
    *(u16x8*)(D + (long)(m0+r)*dstLd + gidx*8) = v;
  }
}

// ---------------- K0 (merged): exe-prep + W1t/W2t transposes + St ------------
// blocks: [0,4) exe_prep | [4,292) W1 tpose | [292,580) W2 tpose | [580,596) St
__global__ __launch_bounds__(256) void prep_k(
    const float* __restrict__ exe, const float* __restrict__ S,
    const float* __restrict__ W1, const float* __restrict__ W2,
    float* __restrict__ exeF, float* __restrict__ zl, u16* __restrict__ Xt,
    u16* __restrict__ St, float* __restrict__ W1t, float* __restrict__ W2t){
  __shared__ __align__(16) char sbuf[9216];
  int id = blockIdx.x, t = threadIdx.x;
  if (id < 4){
    float* em = (float*)sbuf;
    int b = id;
    const float* p = exe + (b*CC + t)*49;
    float s = 0.f;
    for (int i = 0; i < 49; i++) s += p[i];
    float m = s / 49.f;
    em[t] = m;
    exeF[b*CC + t] = m;
    u16* xb = Xt + (size_t)b*XTROWS*CC;
    xb[(size_t)CHW*CC + t] = f2b(m);        // exemplar row (row&7==0: no swizzle)
    for (int i = 0; i < 63; i++)            // zero pad rows 4097..4159
      xb[(size_t)(CHW + 1 + i)*CC + t] = 0;
    __syncthreads();
    const float* Sr = S + (long)t*CC;
    float z = 0.f;
    for (int d = 0; d < CC; d++) z += Sr[d] * em[d];
    zl[b*CC + t] = z;
  } else if (id < 292){
    int i = id - 4;
    tpose_body(W1, W1t, CHID, 257, i % 9, i / 9, sbuf);
  } else if (id < 580){
    int i = id - 292;
    tpose_body(W2, W2t, 257, CHID, i % 32, i / 32, sbuf);
  } else {
    int i = id - 580;
    t64_body(S, St, CC, 0, CC, 0, 0, i & 3, i >> 2, 0, sbuf);
  }
}

// ---------------- K1 (merged): img->Xt transpose + vconv + heat2 -------------
// blocks: [0,1024) t64 img | [1024,2048) vconv | [2048,2112) heat2
__global__ __launch_bounds__(256) void big_k(
    const float* __restrict__ img, const float* __restrict__ exeF,
    const float* __restrict__ zl, u16* __restrict__ Xt, u16* __restrict__ Vb,
    float* __restrict__ heat, float* __restrict__ out_img){
  __shared__ __align__(16) char sbuf[9216];
  int id = blockIdx.x, t = threadIdx.x;
  if (id < 1024){
    int bx = id & 3, by = (id >> 2) & 63, bz = id >> 8;
    t64_body(img, Xt, CHW, (long)CC*CHW, CC, (long)XTROWS*CC, 1, bx, by, bz, sbuf);
  } else if (id < 2048){
    int rc = id - 1024;                  // b*256 + c
    int c = rc & 255;
    const float* srcrow = img + (long)rc*CHW;
    u16* drow = Vb + (long)rc*VROW;
    int cx = c & 7;
    for (int grp = t; grp < VROW/8; grp += 256){
      int G = (grp & ~7) | ((grp & 7) ^ cx);
      int col0 = G*8;
      u16x8 v;
      if (col0 + 8 <= CHW){
        f32x4 a0 = *(const f32x4*)(srcrow + col0);
        f32x4 a1 = *(const f32x4*)(srcrow + col0 + 4);
        v = cvt8(a0, a1);
      } else {
        v = zero8();
        if (col0 == CHW) v[0] = f2b(exeF[rc]);
      }
      *(u16x8*)(drow + grp*8) = v;
    }
  } else {
    int i = id - 2048;
    int bx = i & 15, b = i >> 4;
    float* z = (float*)sbuf;
    z[t] = zl[b*CC + t];
    __syncthreads();
    int m = bx*256 + t;
    const float* base = img + (long)b*CC*CHW + m;
    float s = 0.f;
    for (int c = 0; c < CC; c++) s += base[(long)c*CHW] * z[c];
    heat[b*CHW + m] = s;
    out_img[(long)b*257*CHW + (long)256*CHW + m] = s;
  }
}

// ---------------- K3: NMS + top-150 (bitonic, value desc / index asc) --------
__global__ __launch_bounds__(1024) void topk_k(const float* __restrict__ heat,
                                               int* __restrict__ qids,
                                               float* __restrict__ out_coords){
  int b = blockIdx.x, t = threadIdx.x;
  __shared__ unsigned long long sk[4096];
  const float* hb = heat + (long)b*CHW;
  for (int p = t; p < 4096; p += 1024){
    int i = p >> 6, j = p & 63;
    float h = hb[p];
    bool ismax = false;
    if (i >= 1 && i < 63 && j >= 1 && j < 63){
      ismax = (h >= hb[p+64]) && (h > hb[p-64]) && (h >= hb[p+1]) && (h > hb[p-1]);
    }
    float sup = ismax ? h : (h - 1e9f);
    unsigned u = __float_as_uint(sup);
    u = (u & 0x80000000u) ? ~u : (u | 0x80000000u);
    unsigned long long key = ((unsigned long long)u << 32) | (unsigned)(0xFFFFFFFFu - (unsigned)p);
    sk[p] = ~key;                       // ascending sort of ~key == desired order
  }
  __syncthreads();
  for (int k = 2; k <= 4096; k <<= 1){
    for (int j = k >> 1; j > 0; j >>= 1){
      for (int tt = t; tt < 2048; tt += 1024){
        int i1 = 2*tt - (tt & (j-1));
        int i2 = i1 + j;
        unsigned long long a = sk[i1], c = sk[i2];
        bool up = ((i1 & k) == 0);
        if (up ? (a > c) : (a < c)){ sk[i1] = c; sk[i2] = a; }
      }
      __syncthreads();
    }
  }
  if (t < NQP){
    unsigned long long key = ~sk[t];
    int p = (int)(0xFFFFFFFFu - (unsigned)(key & 0xFFFFFFFFull));
    qids[b*160 + t] = p;
    out_coords[((long)b*NQP + t)*2 + 0] = (float)(p >> 6);
    out_coords[((long)b*NQP + t)*2 + 1] = (float)(p & 63);
  }
}

// ---------------- K4: MFMA flash attention (R4/R5 best structure) ------------
// 512 threads = 8 waves = 4 M x 2 N-halves; wave-local online softmax, end
// merge. Double-buffered LDS + async glds16 staging from pre-swizzled Xt/Vb:
// loads issued at loop top fly during compute; 1 barrier/tile. Query-row
// scatter moved OUT (qhead1 gathers from out_img) — no qids dependency.
__global__ __launch_bounds__(512, 2) void flash_k(
    const u16* __restrict__ Xt, const u16* __restrict__ St,
    const u16* __restrict__ Vb, const float* __restrict__ imgf,
    const float* __restrict__ maskp, const float* __restrict__ Wv,
    float* __restrict__ out_img){
  // LDS carve:
  //   [0,32768)        kp0  u16[64][256]  : K buf0; Q round-trip; final T
  //   [32768,65536)    kt0  u16[256][64]  : V^T buf0
  //   [65536,98304)    kp1  u16[64][256]  : K buf1
  //   [98304,131072)   kt1  u16[256][64]  : V^T buf1
  //   [131072,139264)  p_tile u16[64][64] : P tile (per-wave private)
  //   [139264,143360)  maskb  u8[4096]    : mask row
  //   [143360,144384)  mlx  f32[4][2][16][2] : (m,l) exchange for merge
  __shared__ __align__(16) char smem[144384];
  u16*   kp0 = (u16*)smem;
  u16*   kt0 = (u16*)(smem + 32768);
  u16*   kp1 = (u16*)(smem + 65536);
  u16*   kt1 = (u16*)(smem + 98304);
  u16*   p_tile = (u16*)(smem + 131072);
  unsigned char* maskb = (unsigned char*)(smem + 139264);
  float* mlx = (float*)(smem + 143360);

  int b = blockIdx.y;
  int m0 = blockIdx.x*64;
  int t = threadIdx.x;
  int lane = t & 63, l15 = lane & 15, qd = lane >> 4;
  int w = t >> 6, wm = w & 3, wn = w >> 2;
  f32x4 zero4 = {0.f,0.f,0.f,0.f};

  // ---- stage mask row into LDS as packed u8 (512 thr x 8 px) ----
  {
    const float* mp = maskp + (long)b*CHW + t*8;
    f32x4 a0 = *(const f32x4*)mp;
    f32x4 a1 = *(const f32x4*)(mp + 4);
    unsigned long long pk = 0;
    #pragma unroll
    for (int e = 0; e < 4; e++){
      pk |= (unsigned long long)(a0[e] == 1.0f ? 1u : 0u) << (8*e);
      pk |= (unsigned long long)(a1[e] == 1.0f ? 1u : 0u) << (8*(e+4));
    }
    *(unsigned long long*)&maskb[t*8] = pk;
  }

  const u16* xtb = Xt + (size_t)b*XTROWS*CC;
  const u16* vbb = Vb + (size_t)b*CC*VROW;

  // ---- Phase 0: Q[64][256] = Xrows · St^T (Xt is group-swizzled: XOR addr) --
  {
    f32x4 D[8];
    #pragma unroll
    for (int i = 0; i < 8; i++) D[i] = zero4;
    const u16* arow = xtb + (long)(m0 + wm*16 + l15)*CC;
    int rsw = (l15 & 7)*4;
    #pragma unroll
    for (int ks = 0; ks < 8; ks++){
      u16x8 af = *(const u16x8*)(arow + ((ks*4 + qd) ^ rsw)*8);
      #pragma unroll
      for (int ds = 0; ds < 8; ds++){
        int dsg = wn*8 + ds;
        u16x8 bf_ = *(const u16x8*)(St + (long)(dsg*16 + l15)*CC + ks*32 + qd*8);
        D[ds] = mfma16(af, bf_, D[ds]);
      }
    }
    #pragma unroll
    for (int ds = 0; ds < 8; ds++){
      #pragma unroll
      for (int r = 0; r < 4; r++){
        int prow = wm*16 + qd*4 + r;
        int ccol = (wn*8 + ds)*16 + l15;
        kp0[prow*256 + ((ccol >> 3) ^ ((prow & 7)*4))*8 + (ccol & 7)] = f2b(D[ds][r]);
      }
    }
  }
  __syncthreads();
  u16x8 afrag[8];
  {
    int arl = wm*16 + l15;
    #pragma unroll
    for (int ks = 0; ks < 8; ks++)
      afrag[ks] = *(const u16x8*)&kp0[arl*256 + (((ks*4 + qd)) ^ ((arl & 7)*4))*8];
  }
  int rowAllowed[4];
  float mi[4], li[4];
  #pragma unroll
  for (int r = 0; r < 4; r++){
    int m = m0 + wm*16 + qd*4 + r;
    rowAllowed[r] = maskb[m];
    mi[r] = -1e30f; li[r] = 0.f;
  }
  f32x4 O[16];
  #pragma unroll
  for (int i = 0; i < 16; i++) O[i] = zero4;
  __syncthreads();   // afrag reads done before staging overwrites kp0

  // ---- prologue: async-stage tile 0 into buf0 ----
  {
    const u16* ksrc = xtb + w*2048 + lane*8;
    u16* kl = kp0 + w*2048;
    glds16(ksrc,        kl);
    glds16(ksrc + 512,  kl + 512);
    glds16(ksrc + 1024, kl + 1024);
    glds16(ksrc + 1536, kl + 1536);
    const u16* vsrc = vbb + (long)(w*32 + (lane >> 3))*VROW + (lane & 7)*8;
    u16* vl = kt0 + w*2048;
    glds16(vsrc,            vl);
    glds16(vsrc + 8*VROW,   vl + 512);
    glds16(vsrc + 16*VROW,  vl + 1024);
    glds16(vsrc + 24*VROW,  vl + 1536);
  }
  __syncthreads();   // drains vmcnt -> tile 0 ready

  for (int nt = 0; nt < 65; nt++){
    int cur = nt & 1;
    const u16* kpc = cur ? kp1 : kp0;
    const u16* ktc = cur ? kt1 : kt0;
    u16* kpn = cur ? kp0 : kp1;
    u16* ktn = cur ? kt0 : kt1;
    int n0 = nt*64;

    // ---- ISSUE next tile's async loads (fly during this tile's compute) ----
    if (nt < 64){
      int n1 = n0 + 64;
      const u16* ksrc = xtb + (long)n1*CC + w*2048 + lane*8;
      u16* kl = kpn + w*2048;
      glds16(ksrc,        kl);
      glds16(ksrc + 512,  kl + 512);
      glds16(ksrc + 1024, kl + 1024);
      glds16(ksrc + 1536, kl + 1536);
      const u16* vsrc = vbb + (long)(w*32 + (lane >> 3))*VROW + n1 + (lane & 7)*8;
      u16* vl = ktn + w*2048;
      glds16(vsrc,            vl);
      glds16(vsrc + 8*VROW,   vl + 512);
      glds16(vsrc + 16*VROW,  vl + 1024);
      glds16(vsrc + 24*VROW,  vl + 1536);
    }

    // ---- QK^T (this wave's 32-column half) on buf[cur] ----
    f32x4 sc[2];
    sc[0] = zero4; sc[1] = zero4;
    __builtin_amdgcn_s_setprio(1);
    #pragma unroll
    for (int ks = 0; ks < 8; ks++){
      #pragma unroll
      for (int ns = 0; ns < 2; ns++){
        int n_l = (wn*2 + ns)*16 + l15;
        u16x8 bfrag = *(const u16x8*)&kpc[n_l*256 + (((ks*4 + qd)) ^ ((n_l & 7)*4))*8];
        sc[ns] = mfma16(afrag[ks], bfrag, sc[ns]);
      }
    }
    __builtin_amdgcn_s_setprio(0);

    // ---- mask bias + online softmax (wave-local, own half) ----
    float sEff[2][4];
    #pragma unroll
    for (int ns = 0; ns < 2; ns++){
      int n = n0 + (wn*2 + ns)*16 + l15;
      bool inv = (n >= CNQ);
      bool isEx = (n == CHW);
      int cm = 0;
      if (!inv && !isEx) cm = maskb[n];
      #pragma unroll
      for (int r = 0; r < 4; r++){
        float s = sc[ns][r];
        float se;
        if (inv)        se = -1e30f;
        else if (isEx)  se = s;
        else            se = (rowAllowed[r] & cm) ? s : s - 1e9f;
        sEff[ns][r] = se;
      }
    }
    float al[4], nm[4];
    #pragma unroll
    for (int r = 0; r < 4; r++){
      float tm = fmaxf(sEff[0][r], sEff[1][r]);
      #pragma unroll
      for (int d = 1; d < 16; d <<= 1) tm = fmaxf(tm, __shfl_xor(tm, d, 16));
      float newm = fmaxf(mi[r], tm);
      al[r] = (mi[r] < -1e29f) ? 0.f : __expf(fmaxf(mi[r] - newm, -88.f));
      nm[r] = newm; mi[r] = newm;
    }
    #pragma unroll
    for (int r = 0; r < 4; r++){
      float rs = 0.f;
      int prow = wm*16 + qd*4 + r;
      #pragma unroll
      for (int ns = 0; ns < 2; ns++){
        float p = __expf(fmaxf(sEff[ns][r] - nm[r], -88.f));
        rs += p;
        int ccol = (wn*2 + ns)*16 + l15;
        p_tile[prow*64 + ((ccol >> 3) ^ (prow & 7))*8 + (ccol & 7)] = f2b(p);
      }
      #pragma unroll
      for (int d = 1; d < 16; d <<= 1) rs += __shfl_xor(rs, d, 16);
      li[r] = li[r]*al[r] + rs;
    }
    // P writes/reads are wave-private regions: no barrier, just drain LDS.
    asm volatile("s_waitcnt lgkmcnt(0)" ::: "memory");

    // ---- rescale T only when the running max actually moved (al!=1) ----
    int needre = (al[0] != 1.f) | (al[1] != 1.f) | (al[2] != 1.f) | (al[3] != 1.f);
    if (__any(needre)){
      #pragma unroll
      for (int ds = 0; ds < 16; ds++){
        #pragma unroll
        for (int r = 0; r < 4; r++) O[ds][r] *= al[r];
      }
    }
    // ---- T += P·Vtile over this wave's 32-column half ----
    {
      int prow2 = wm*16 + l15;
      u16x8 pf = *(const u16x8*)&p_tile[prow2*64 + (((wn*4 + qd)) ^ (prow2 & 7))*8];
      __builtin_amdgcn_s_setprio(1);
      #pragma unroll
      for (int ds = 0; ds < 16; ds++){
        int c = ds*16 + l15;
        u16x8 vf = *(const u16x8*)&ktc[c*64 + (((wn*4 + qd)) ^ (c & 7))*8];
        O[ds] = mfma16(pf, vf, O[ds]);
      }
      __builtin_amdgcn_s_setprio(0);
    }
    __syncthreads();   // buf[cur] reads done; drains vmcnt -> buf[cur^1] ready
  }

  // ---- merge the two N-halves (flash-decoding in-block merge) ----
  if (l15 == 0){
    #pragma unroll
    for (int r = 0; r < 4; r++){
      mlx[(((wm*2 + wn)*16) + qd*4 + r)*2 + 0] = mi[r];
      mlx[(((wm*2 + wn)*16) + qd*4 + r)*2 + 1] = li[r];
    }
  }
  __syncthreads();
  float alpha[4], linv[4];
  #pragma unroll
  for (int r = 0; r < 4; r++){
    float mo = mlx[(((wm*2 + (1 - wn))*16) + qd*4 + r)*2 + 0];
    float lo = mlx[(((wm*2 + (1 - wn))*16) + qd*4 + r)*2 + 1];
    float ms = fmaxf(mi[r], mo);
    float aS = (mi[r] < -1e29f) ? 0.f : __expf(mi[r] - ms);
    float aO = (mo    < -1e29f) ? 0.f : __expf(mo - ms);
    float ls = li[r]*aS + lo*aO;
    alpha[r] = aS;
    linv[r] = (ls > 0.f) ? (1.0f / ls) : 0.f;
  }
  float* Tsum = (float*)smem;         // 64KB f32 scratch spanning kp0+kt0
  if (wn == 1){
    #pragma unroll
    for (int ds = 0; ds < 16; ds++){
      #pragma unroll
      for (int r = 0; r < 4; r++)
        Tsum[(wm*16 + qd*4 + r)*256 + ds*16 + l15] = O[ds][r]*alpha[r];
    }
  }
  __syncthreads();
  if (wn == 0){
    #pragma unroll
    for (int ds = 0; ds < 16; ds++){
      #pragma unroll
      for (int r = 0; r < 4; r++)
        O[ds][r] = (O[ds][r]*alpha[r] + Tsum[(wm*16 + qd*4 + r)*256 + ds*16 + l15]) * linv[r];
    }
  }
  __syncthreads();                    // Tsum reads done before bf16 overwrite
  if (wn == 0){
    #pragma unroll
    for (int ds = 0; ds < 16; ds++){
      #pragma unroll
      for (int r = 0; r < 4; r++){
        int prow = wm*16 + qd*4 + r;
        int ccol = ds*16 + l15;
        kp0[prow*256 + ((ccol >> 3) ^ ((prow & 7)*4))*8 + (ccol & 7)] = f2b(O[ds][r]);
      }
    }
  }
  __syncthreads();
  u16x8 tfrag[8];
  {
    int arl = wm*16 + l15;
    #pragma unroll
    for (int ks = 0; ks < 8; ks++)
      tfrag[ks] = *(const u16x8*)&kp0[arl*256 + (((ks*4 + qd)) ^ ((arl & 7)*4))*8];
  }
  // ---- final projection F = T_norm · Wv^T, ds split between halves ----
  f32x4 F[8];
  #pragma unroll
  for (int i = 0; i < 8; i++) F[i] = zero4;
  #pragma unroll
  for (int ks = 0; ks < 8; ks++){
    #pragma unroll
    for (int ds = 0; ds < 8; ds++){
      int dsg = wn*8 + ds;
      const float* wr = Wv + (long)(dsg*16 + l15)*CC + ks*32 + qd*8;
      f32x4 w0 = *(const f32x4*)wr;
      f32x4 w1 = *(const f32x4*)(wr + 4);
      F[ds] = mfma16(tfrag[ks], cvt8(w0, w1), F[ds]);
    }
  }

  // ---- epilogue: f32 img_out only (query rows gathered later by qhead1) ----
  float* oi = out_img + (long)b*257*CHW;
  const float* fi = imgf + (long)b*CC*CHW;
  int mb = m0 + wm*16 + qd*4;
  #pragma unroll
  for (int ds = 0; ds < 8; ds++){
    int d = (wn*8 + ds)*16 + l15;
    f32x4 ivals = *(const f32x4*)(fi + (long)d*CHW + mb);
    f32x4 ovals;
    #pragma unroll
    for (int r = 0; r < 4; r++) ovals[r] = F[ds][r] + ivals[r];
    *(f32x4*)(oi + (long)d*CHW + mb) = ovals;
  }
}

// ---------------- K5a: gather + LN + layer1 chunk (broadcast GEMV) -----------
// Rows gathered directly from out_img via qids (replaces flash's scatter).
__global__ __launch_bounds__(256) void qhead1_k(const float* __restrict__ out_img,
    const int* __restrict__ qids,
    const float* __restrict__ g, const float* __restrict__ be,
    const float* __restrict__ W1t, const float* __restrict__ b1,
    float* __restrict__ Hb){
  int hc = blockIdx.x, rb = blockIdx.y;
  int t = threadIdx.x, lane = t & 63, wv = t >> 6;
  __shared__ __align__(16) float xl[4][260];
  // ---- gather + LN: wave wv handles global row rb*4+wv ----
  {
    int gq = rb*4 + wv;
    int b = gq / NQP, q = gq - b*NQP;
    int m = qids[b*160 + q];
    const float* oib = out_img + (long)b*257*CHW + m;
    float v[4];
    #pragma unroll
    for (int j = 0; j < 4; j++) v[j] = oib[(long)(lane + j*64)*CHW];
    float v4 = (lane == 0) ? oib[(long)256*CHW] : 0.f;
    float s = v[0]+v[1]+v[2]+v[3]+v4;
    #pragma unroll
    for (int d = 1; d < 64; d <<= 1) s += __shfl_xor(s, d, 64);
    float mu = s / 257.f;
    float d4 = (lane == 0) ? (v4 - mu) : 0.f;
    float vs = d4*d4;
    #pragma unroll
    for (int j = 0; j < 4; j++){ float dd = v[j]-mu; vs += dd*dd; }
    #pragma unroll
    for (int d = 1; d < 64; d <<= 1) vs += __shfl_xor(vs, d, 64);
    float inv = 1.0f / sqrtf(vs/257.f + 1e-5f);
    #pragma unroll
    for (int j = 0; j < 4; j++)
      xl[wv][lane + j*64] = (v[j]-mu)*inv*g[lane + j*64] + be[lane + j*64];
    if (lane == 0) xl[wv][256] = d4*inv*g[256] + be[256];
  }
  __syncthreads();
  int h = hc*256 + t;
  float acc0=0.f, acc1=0.f, acc2=0.f, acc3=0.f;
  #pragma unroll 8
  for (int c = 0; c < 256; c++){
    float wv_ = W1t[(long)c*CHID + h];
    acc0 += wv_*xl[0][c]; acc1 += wv_*xl[1][c];
    acc2 += wv_*xl[2][c]; acc3 += wv_*xl[3][c];
  }
  {
    float wv_ = W1t[(long)256*CHID + h];
    acc0 += wv_*xl[0][256]; acc1 += wv_*xl[1][256];
    acc2 += wv_*xl[2][256]; acc3 += wv_*xl[3][256];
  }
  float bb = b1[h];
  float* hb = Hb + (long)rb*4*CHID + h;
  hb[0]       = fmaxf(acc0 + bb, 0.f);
  hb[CHID]    = fmaxf(acc1 + bb, 0.f);
  hb[2*CHID]  = fmaxf(acc2 + bb, 0.f);
  hb[3*CHID]  = fmaxf(acc3 + bb, 0.f);
}

// ---------------- K5b: layer2 (broadcast GEMV, coalesced W2t) ----------------
__global__ __launch_bounds__(256) void qhead2_k(float* __restrict__ qbuf,
    const float* __restrict__ Hb, const float* __restrict__ W2t,
    const float* __restrict__ b2){
  int rb = blockIdx.x;
  int t = threadIdx.x, lane = t & 63, wv = t >> 6;
  __shared__ __align__(16) float hl[4][CHID];
  const float* hs = Hb + (long)rb*4*CHID;
  #pragma unroll
  for (int q = 0; q < 4; q++)
    *(f32x4*)&hl[q][t*4] = *(const f32x4*)&hs[(long)q*CHID + t*4];
  __syncthreads();
  float a0=0.f, a1=0.f, a2=0.f, a3=0.f;
  #pragma unroll 8
  for (int c = 0; c < CHID; c++){
    float wv_ = W2t[(long)c*257 + t];
    a0 += wv_*hl[0][c]; a1 += wv_*hl[1][c];
    a2 += wv_*hl[2][c]; a3 += wv_*hl[3][c];
  }
  float bb = b2[t];
  qbuf[(long)(rb*4 + 0)*257 + t] = a0 + bb;
  qbuf[(long)(rb*4 + 1)*257 + t] = a1 + bb;
  qbuf[(long)(rb*4 + 2)*257 + t] = a2 + bb;
  qbuf[(long)(rb*4 + 3)*257 + t] = a3 + bb;
  // ---- o = 256 handled by wave 0: 16 c's per lane, shuffle reduce ----
  if (wv == 0){
    float p0=0.f, p1=0.f, p2=0.f, p3=0.f;
    #pragma unroll
    for (int k = 0; k < 16; k++){
      int c = lane*16 + k;
      float wv_ = W2t[(long)c*257 + 256];
      p0 += wv_*hl[0][c]; p1 += wv_*hl[1][c];
      p2 += wv_*hl[2][c]; p3 += wv_*hl[3][c];
    }
    #pragma unroll
    for (int d = 1; d < 64; d <<= 1){
      p0 += __shfl_xor(p0, d, 64); p1 += __shfl_xor(p1, d, 64);
      p2 += __shfl_xor(p2, d, 64); p3 += __shfl_xor(p3, d, 64);
    }
    if (lane == 0){
      float b256 = b2[256];
      qbuf[(long)(rb*4 + 0)*257 + 256] = p0 + b256;
      qbuf[(long)(rb*4 + 1)*257 + 256] = p1 + b256;
      qbuf[(long)(rb*4 + 2)*257 + 256] = p2 + b256;
      qbuf[(long)(rb*4 + 3)*257 + 256] = p3 + b256;
    }
  }
}

// ---------------- launch: input mapping by SIZE (robust to ordering) ---------
extern "C" void kernel_launch(void* const* d_in, const int* in_sizes, int n_in,
                              void* d_out, int out_size, void* d_ws, size_t ws_size,
                              hipStream_t stream){
  (void)out_size; (void)ws_size;
  int idxImg=-1, idxExe=-1, idxMask=-1, idxB1=-1;
  int idx65[2]={-1,-1}; int n65=0;
  int idx263[2]={-1,-1}; int n263=0;
  int idx257[3]={-1,-1,-1}; int n257=0;
  for (int i = 0; i < n_in; i++){
    int s = in_sizes[i];
    if      (s == 4194304) idxImg = i;
    else if (s == 50176)   idxExe = i;
    else if (s == 16384)   idxMask = i;
    else if (s == 1024)    idxB1 = i;
    else if (s == 65536)  { if (n65 < 2)  idx65[n65++] = i; }
    else if (s == 263168) { if (n263 < 2) idx263[n263++] = i; }
    else if (s == 257)    { if (n257 < 3) idx257[n257++] = i; }
  }
  const float* img  = (const float*)d_in[idxImg];
  const float* exe  = (const float*)d_in[idxExe];
  const float* mask = (const float*)d_in[idxMask];
  const float* S    = (const float*)d_in[idx65[0]];   // S before Wv in both dict & sorted order
  const float* Wv   = (const float*)d_in[idx65[1]];
  const float* W1   = (const float*)d_in[idx263[0]];  // W1 before W2 in both orders
  const float* W2   = (const float*)d_in[idx263[1]];
  const float* b1   = (const float*)d_in[idxB1];
  const float *lng, *lnb, *b2;
  if (idxImg == 0){           // dict order: ln_g, ln_b, b2
    lng = (const float*)d_in[idx257[0]];
    lnb = (const float*)d_in[idx257[1]];
    b2  = (const float*)d_in[idx257[2]];
  } else {                    // name-sorted: b2, ln_b, ln_g
    b2  = (const float*)d_in[idx257[0]];
    lnb = (const float*)d_in[idx257[1]];
    lng = (const float*)d_in[idx257[2]];
  }

  char* ws = (char*)d_ws;
  u16*   Xt   = (u16*)(ws + XT_OFF);
  u16*   Vb   = (u16*)(ws + VB_OFF);
  u16*   St   = (u16*)(ws + ST_OFF);
  float* exeF = (float*)(ws + EXE_OFF);
  float* zl   = (float*)(ws + ZL_OFF);
  float* heat = (float*)(ws + HEAT_OFF);
  int*   qids = (int*)(ws + QID_OFF);
  float* W1t  = (float*)(ws + W1T_OFF);
  float* W2t  = (float*)(ws + W2T_OFF);
  float* Hb   = (float*)(ws + HB_OFF);

  float* out      = (float*)d_out;                       // f32 outputs
  float* out_img  = out;                                 // [4][257][4096]
  float* qbuf     = out + (size_t)CB*257*CHW;            // [4][150][257]
  float* out_crd  = qbuf + (size_t)CB*NQP*257;           // [4][150][2]

  prep_k<<<dim3(596), dim3(256), 0, stream>>>(
      exe, S, W1, W2, exeF, zl, Xt, St, W1t, W2t);
  big_k<<<dim3(2112), dim3(256), 0, stream>>>(
      img, exeF, zl, Xt, Vb, heat, out_img);
  topk_k<<<dim3(CB), dim3(1024), 0, stream>>>(heat, qids, out_crd);
  flash_k<<<dim3(64, CB), dim3(512), 0, stream>>>(
      Xt, St, Vb, img, mask, Wv, out_img);
  qhead1_k<<<dim3(4, CB*NQP/4), dim3(256), 0, stream>>>(
      out_img, qids, lng, lnb, W1t, b1, Hb);
  qhead2_k<<<dim3(CB*NQP/4), dim3(256), 0, stream>>>(qbuf, Hb, W2t, b2);
}

// Round 9
// 398.698 us; speedup vs baseline: 1.2718x; 1.0676x over previous
//
#include <hip/hip_runtime.h>
#include <hip/hip_bf16.h>
#include <stdint.h>

typedef unsigned short u16;
typedef unsigned int u32;
typedef unsigned long long u64;
typedef __attribute__((ext_vector_type(8))) unsigned short u16x8;
typedef __attribute__((ext_vector_type(8))) short short8;
typedef __attribute__((ext_vector_type(4))) float f32x4;

#define CB   4
#define CC   256
#define CHW  4096
#define CNQ  4097
#define NQP  150
#define CHID 1024
#define XTROWS 4160   // 4096 img rows + exemplar + 63 zero pad (65 tiles of 64)
#define VROW   4160   // V cols padded to 65 tiles of 64

// ---------------- workspace layout (bytes) ----------------
#define XT_OFF   0ul                                        // bf16 [B][4160][256] swizzled
#define VB_OFF   (XT_OFF  + (size_t)CB*XTROWS*CC*2)         // bf16 [B][256][4160] swizzled
#define ST_OFF   (VB_OFF  + (size_t)CB*CC*VROW*2)           // bf16 [256][256] (S^T)
#define EXE_OFF  (ST_OFF  + 131072ul)                       // f32  [B][256]
#define ZL_OFF   (EXE_OFF + 4096ul)                         // f32  [B][256]  (S·em)
#define HEAT_OFF (ZL_OFF  + 4096ul)                         // f32  [B][4096]
#define QID_OFF  (HEAT_OFF+ 65536ul)                        // int  [B][160]
#define W1T_OFF  (QID_OFF + 2560ul)                         // f32  [257][1024]
#define W2T_OFF  (W1T_OFF + 1052672ul)                      // f32  [1024][257]
#define HB_OFF   (W2T_OFF + 1052672ul)                      // f32  [600][1024]
#define QG_OFF   (HB_OFF  + 2457600ul)                      // f32  [600][257] gathered q rows

__device__ __forceinline__ u16 f2b(float f){
  __hip_bfloat16 h = __float2bfloat16(f); u16 r; __builtin_memcpy(&r, &h, 2); return r;
}
__device__ __forceinline__ f32x4 mfma16(u16x8 a, u16x8 b, f32x4 c){
  short8 as, bs; __builtin_memcpy(&as, &a, 16); __builtin_memcpy(&bs, &b, 16);
  return __builtin_amdgcn_mfma_f32_16x16x32_bf16(as, bs, c, 0, 0, 0);
}
__device__ __forceinline__ u16x8 zero8(){
  u16x8 v;
  #pragma unroll
  for (int e = 0; e < 8; e++) v[e] = 0;
  return v;
}
__device__ __forceinline__ u16x8 cvt8(f32x4 a, f32x4 b){
  u16x8 v;
  v[0]=f2b(a[0]); v[1]=f2b(a[1]); v[2]=f2b(a[2]); v[3]=f2b(a[3]);
  v[4]=f2b(b[0]); v[5]=f2b(b[1]); v[6]=f2b(b[2]); v[7]=f2b(b[3]);
  return v;
}
// async global->LDS, 16B per lane; LDS dest = wave-uniform base + lane*16
__device__ __forceinline__ void glds16(const u16* gp, u16* lp){
  __builtin_amdgcn_global_load_lds(
      (const __attribute__((address_space(1))) u32*)gp,
      (__attribute__((address_space(3))) u32*)lp, 16, 0, 0);
}

// ---- 16-lane reduce, pure-VALU DPP (masks {1,2,7,15} span the 4-bit group;
// DPP row = 16 lanes = exactly our l15-aligned groups; no LDS swizzle ops) ----
__device__ __forceinline__ float dppx(float x, const int ctrl){
  // ctrl must be a compile-time literal at each call site
  return x; // overridden by macro below
}
#define DPPF(x, ctrl) __int_as_float(__builtin_amdgcn_mov_dpp(__float_as_int(x), (ctrl), 0xF, 0xF, true))
__device__ __forceinline__ float red16_max(float x){
  x = fmaxf(x, DPPF(x, 0xB1));   // quad_perm [1,0,3,2]  = xor1
  x = fmaxf(x, DPPF(x, 0x4E));   // quad_perm [2,3,0,1]  = xor2
  x = fmaxf(x, DPPF(x, 0x141));  // row_half_mirror      = xor7
  x = fmaxf(x, DPPF(x, 0x140));  // row_mirror           = xor15
  return x;
}
__device__ __forceinline__ float red16_sum(float x){
  x += DPPF(x, 0xB1);
  x += DPPF(x, 0x4E);
  x += DPPF(x, 0x141);
  x += DPPF(x, 0x140);
  return x;
}

// ---------------- shared helper bodies (block-uniform branch safe) -----------
__device__ __forceinline__ void tpose_body(const float* __restrict__ src,
    float* __restrict__ dst, int R, int C, int bx, int by, char* sbuf){
  float (*tile)[33] = (float(*)[33])sbuf;
  int c0 = bx*32, r0 = by*32;
  int tc = threadIdx.x & 31, tr = threadIdx.x >> 5;   // 8 rows per pass
  for (int i = tr; i < 32; i += 8){
    int r = r0 + i, c = c0 + tc;
    tile[i][tc] = (r < R && c < C) ? src[(long)r*C + c] : 0.f;
  }
  __syncthreads();
  for (int i = tr; i < 32; i += 8){
    int c = c0 + i, r = r0 + tc;
    if (c < C && r < R) dst[(long)c*R + r] = tile[tc][i];
  }
}

// 64x64 tiled transpose, f32 src -> bf16 dst; swz=1 bakes flash's K XOR swizzle
__device__ __forceinline__ void t64_body(const float* __restrict__ src,
    u16* __restrict__ dst, int srcLd, long srcBatch, int dstLd, long dstBatch,
    int swz, int bx, int by, int bz, char* sbuf){
  u16 (*tile)[72] = (u16(*)[72])sbuf;
  int c0 = bx*64, m0 = by*64;
  const float* S = src + (long)bz*srcBatch;
  u16* D = dst + (long)bz*dstBatch;
  int t = threadIdx.x;
  int r = t >> 2, q = t & 3;
  for (int uu = q; uu < 8; uu += 4){
    const float* p = S + (long)(c0+r)*srcLd + m0 + uu*8;
    f32x4 a0 = *(const f32x4*)p;
    f32x4 a1 = *(const f32x4*)(p + 4);
    *(u16x8*)&tile[r][uu*8] = cvt8(a0, a1);
  }
  __syncthreads();
  for (int uu = q; uu < 8; uu += 4){
    u16x8 v;
    #pragma unroll
    for (int e = 0; e < 8; e++) v[e] = tile[uu*8 + e][r];
    int gidx = (c0 >> 3) + uu;
    if (swz) gidx ^= (r & 7)*4;
    *(u16x8*)(D + (long)(m0+r)*dstLd + gidx*8) = v;
  }
}

// ---------------- K0 (merged): exe-prep + W1t/W2t transposes + St ------------
// blocks: [0,4) exe_prep | [4,292) W1 tpose | [292,580) W2 tpose | [580,596) St
__global__ __launch_bounds__(256) void prep_k(
    const float* __restrict__ exe, const float* __restrict__ S,
    const float* __restrict__ W1, const float* __restrict__ W2,
    float* __restrict__ exeF, float* __restrict__ zl, u16* __restrict__ Xt,
    u16* __restrict__ St, float* __restrict__ W1t, float* __restrict__ W2t){
  __shared__ __align__(16) char sbuf[9216];
  int id = blockIdx.x, t = threadIdx.x;
  if (id < 4){
    float* em = (float*)sbuf;
    int b = id;
    const float* p = exe + (b*CC + t)*49;
    float s = 0.f;
    for (int i = 0; i < 49; i++) s += p[i];
    float m = s / 49.f;
    em[t] = m;
    exeF[b*CC + t] = m;
    u16* xb = Xt + (size_t)b*XTROWS*CC;
    xb[(size_t)CHW*CC + t] = f2b(m);        // exemplar row (row&7==0: no swizzle)
    for (int i = 0; i < 63; i++)            // zero pad rows 4097..4159
      xb[(size_t)(CHW + 1 + i)*CC + t] = 0;
    __syncthreads();
    const float* Sr = S + (long)t*CC;
    float z = 0.f;
    for (int d = 0; d < CC; d++) z += Sr[d] * em[d];
    zl[b*CC + t] = z;
  } else if (id < 292){
    int i = id - 4;
    tpose_body(W1, W1t, CHID, 257, i % 9, i / 9, sbuf);
  } else if (id < 580){
    int i = id - 292;
    tpose_body(W2, W2t, 257, CHID, i % 32, i / 32, sbuf);
  } else {
    int i = id - 580;
    t64_body(S, St, CC, 0, CC, 0, 0, i & 3, i >> 2, 0, sbuf);
  }
}

// ---------------- K1 (merged): img->Xt transpose + vconv + heat2 -------------
// blocks: [0,1024) t64 img | [1024,2048) vconv | [2048,2112) heat2
__global__ __launch_bounds__(256) void big_k(
    const float* __restrict__ img, const float* __restrict__ exeF,
    const float* __restrict__ zl, u16* __restrict__ Xt, u16* __restrict__ Vb,
    float* __restrict__ heat, float* __restrict__ out_img){
  __shared__ __align__(16) char sbuf[9216];
  int id = blockIdx.x, t = threadIdx.x;
  if (id < 1024){
    int bx = id & 3, by = (id >> 2) & 63, bz = id >> 8;
    t64_body(img, Xt, CHW, (long)CC*CHW, CC, (long)XTROWS*CC, 1, bx, by, bz, sbuf);
  } else if (id < 2048){
    int rc = id - 1024;                  // b*256 + c
    int c = rc & 255;
    const float* srcrow = img + (long)rc*CHW;
    u16* drow = Vb + (long)rc*VROW;
    int cx = c & 7;
    for (int grp = t; grp < VROW/8; grp += 256){
      int G = (grp & ~7) | ((grp & 7) ^ cx);
      int col0 = G*8;
      u16x8 v;
      if (col0 + 8 <= CHW){
        f32x4 a0 = *(const f32x4*)(srcrow + col0);
        f32x4 a1 = *(const f32x4*)(srcrow + col0 + 4);
        v = cvt8(a0, a1);
      } else {
        v = zero8();
        if (col0 == CHW) v[0] = f2b(exeF[rc]);
      }
      *(u16x8*)(drow + grp*8) = v;
    }
  } else {
    int i = id - 2048;
    int bx = i & 15, b = i >> 4;
    float* z = (float*)sbuf;
    z[t] = zl[b*CC + t];
    __syncthreads();
    int m = bx*256 + t;
    const float* base = img + (long)b*CC*CHW + m;
    float s = 0.f;
    for (int c = 0; c < CC; c++) s += base[(long)c*CHW] * z[c];
    heat[b*CHW + m] = s;
    out_img[(long)b*257*CHW + (long)256*CHW + m] = s;
  }
}

// ---------------- K3: NMS + top-150 (bitonic, value desc / index asc) --------
__global__ __launch_bounds__(1024) void topk_k(const float* __restrict__ heat,
                                               int* __restrict__ qids,
                                               float* __restrict__ out_coords){
  int b = blockIdx.x, t = threadIdx.x;
  __shared__ unsigned long long sk[4096];
  const float* hb = heat + (long)b*CHW;
  for (int p = t; p < 4096; p += 1024){
    int i = p >> 6, j = p & 63;
    float h = hb[p];
    bool ismax = false;
    if (i >= 1 && i < 63 && j >= 1 && j < 63){
      ismax = (h >= hb[p+64]) && (h > hb[p-64]) && (h >= hb[p+1]) && (h > hb[p-1]);
    }
    float sup = ismax ? h : (h - 1e9f);
    unsigned u = __float_as_uint(sup);
    u = (u & 0x80000000u) ? ~u : (u | 0x80000000u);
    unsigned long long key = ((unsigned long long)u << 32) | (unsigned)(0xFFFFFFFFu - (unsigned)p);
    sk[p] = ~key;                       // ascending sort of ~key == desired order
  }
  __syncthreads();
  for (int k = 2; k <= 4096; k <<= 1){
    for (int j = k >> 1; j > 0; j >>= 1){
      for (int tt = t; tt < 2048; tt += 1024){
        int i1 = 2*tt - (tt & (j-1));
        int i2 = i1 + j;
        unsigned long long a = sk[i1], c = sk[i2];
        bool up = ((i1 & k) == 0);
        if (up ? (a > c) : (a < c)){ sk[i1] = c; sk[i2] = a; }
      }
      __syncthreads();
    }
  }
  if (t < NQP){
    unsigned long long key = ~sk[t];
    int p = (int)(0xFFFFFFFFu - (unsigned)(key & 0xFFFFFFFFull));
    qids[b*160 + t] = p;
    out_coords[((long)b*NQP + t)*2 + 0] = (float)(p >> 6);
    out_coords[((long)b*NQP + t)*2 + 1] = (float)(p & 63);
  }
}

// ---------------- K4: MFMA flash attention (R4/R5 best structure) ------------
// 512 threads = 8 waves = 4 M x 2 N-halves; wave-local online softmax (DPP
// reductions — no LDS swizzles), end merge. Double-buffered LDS + async glds16
// staging from pre-swizzled Xt/Vb; 1 barrier/tile.
__global__ __launch_bounds__(512, 2) void flash_k(
    const u16* __restrict__ Xt, const u16* __restrict__ St,
    const u16* __restrict__ Vb, const float* __restrict__ imgf,
    const float* __restrict__ maskp, const float* __restrict__ Wv,
    float* __restrict__ out_img){
  // LDS carve:
  //   [0,32768)        kp0  u16[64][256]  : K buf0; Q round-trip; final T
  //   [32768,65536)    kt0  u16[256][64]  : V^T buf0
  //   [65536,98304)    kp1  u16[64][256]  : K buf1
  //   [98304,131072)   kt1  u16[256][64]  : V^T buf1
  //   [131072,139264)  p_tile u16[64][64] : P tile (per-wave private)
  //   [139264,143360)  maskb  u8[4096]    : mask row
  //   [143360,144384)  mlx  f32[4][2][16][2] : (m,l) exchange for merge
  __shared__ __align__(16) char smem[144384];
  u16*   kp0 = (u16*)smem;
  u16*   kt0 = (u16*)(smem + 32768);
  u16*   kp1 = (u16*)(smem + 65536);
  u16*   kt1 = (u16*)(smem + 98304);
  u16*   p_tile = (u16*)(smem + 131072);
  unsigned char* maskb = (unsigned char*)(smem + 139264);
  float* mlx = (float*)(smem + 143360);

  int b = blockIdx.y;
  int m0 = blockIdx.x*64;
  int t = threadIdx.x;
  int lane = t & 63, l15 = lane & 15, qd = lane >> 4;
  int w = t >> 6, wm = w & 3, wn = w >> 2;
  f32x4 zero4 = {0.f,0.f,0.f,0.f};

  // ---- stage mask row into LDS as packed u8 (512 thr x 8 px) ----
  {
    const float* mp = maskp + (long)b*CHW + t*8;
    f32x4 a0 = *(const f32x4*)mp;
    f32x4 a1 = *(const f32x4*)(mp + 4);
    unsigned long long pk = 0;
    #pragma unroll
    for (int e = 0; e < 4; e++){
      pk |= (unsigned long long)(a0[e] == 1.0f ? 1u : 0u) << (8*e);
      pk |= (unsigned long long)(a1[e] == 1.0f ? 1u : 0u) << (8*(e+4));
    }
    *(unsigned long long*)&maskb[t*8] = pk;
  }

  const u16* xtb = Xt + (size_t)b*XTROWS*CC;
  const u16* vbb = Vb + (size_t)b*CC*VROW;

  // ---- Phase 0: Q[64][256] = Xrows · St^T (Xt is group-swizzled: XOR addr) --
  {
    f32x4 D[8];
    #pragma unroll
    for (int i = 0; i < 8; i++) D[i] = zero4;
    const u16* arow = xtb + (long)(m0 + wm*16 + l15)*CC;
    int rsw = (l15 & 7)*4;
    #pragma unroll
    for (int ks = 0; ks < 8; ks++){
      u16x8 af = *(const u16x8*)(arow + ((ks*4 + qd) ^ rsw)*8);
      #pragma unroll
      for (int ds = 0; ds < 8; ds++){
        int dsg = wn*8 + ds;
        u16x8 bf_ = *(const u16x8*)(St + (long)(dsg*16 + l15)*CC + ks*32 + qd*8);
        D[ds] = mfma16(af, bf_, D[ds]);
      }
    }
    #pragma unroll
    for (int ds = 0; ds < 8; ds++){
      #pragma unroll
      for (int r = 0; r < 4; r++){
        int prow = wm*16 + qd*4 + r;
        int ccol = (wn*8 + ds)*16 + l15;
        kp0[prow*256 + ((ccol >> 3) ^ ((prow & 7)*4))*8 + (ccol & 7)] = f2b(D[ds][r]);
      }
    }
  }
  __syncthreads();
  u16x8 afrag[8];
  {
    int arl = wm*16 + l15;
    #pragma unroll
    for (int ks = 0; ks < 8; ks++)
      afrag[ks] = *(const u16x8*)&kp0[arl*256 + (((ks*4 + qd)) ^ ((arl & 7)*4))*8];
  }
  int rowAllowed[4];
  float mi[4], li[4];
  #pragma unroll
  for (int r = 0; r < 4; r++){
    int m = m0 + wm*16 + qd*4 + r;
    rowAllowed[r] = maskb[m];
    mi[r] = -1e30f; li[r] = 0.f;
  }
  f32x4 O[16];
  #pragma unroll
  for (int i = 0; i < 16; i++) O[i] = zero4;
  __syncthreads();   // afrag reads done before staging overwrites kp0

  // ---- prologue: async-stage tile 0 into buf0 ----
  {
    const u16* ksrc = xtb + w*2048 + lane*8;
    u16* kl = kp0 + w*2048;
    glds16(ksrc,        kl);
    glds16(ksrc + 512,  kl + 512);
    glds16(ksrc + 1024, kl + 1024);
    glds16(ksrc + 1536, kl + 1536);
    const u16* vsrc = vbb + (long)(w*32 + (lane >> 3))*VROW + (lane & 7)*8;
    u16* vl = kt0 + w*2048;
    glds16(vsrc,            vl);
    glds16(vsrc + 8*VROW,   vl + 512);
    glds16(vsrc + 16*VROW,  vl + 1024);
    glds16(vsrc + 24*VROW,  vl + 1536);
  }
  __syncthreads();   // drains vmcnt -> tile 0 ready

  for (int nt = 0; nt < 65; nt++){
    int cur = nt & 1;
    const u16* kpc = cur ? kp1 : kp0;
    const u16* ktc = cur ? kt1 : kt0;
    u16* kpn = cur ? kp0 : kp1;
    u16* ktn = cur ? kt0 : kt1;
    int n0 = nt*64;

    // ---- ISSUE next tile's async loads (fly during this tile's compute) ----
    if (nt < 64){
      int n1 = n0 + 64;
      const u16* ksrc = xtb + (long)n1*CC + w*2048 + lane*8;
      u16* kl = kpn + w*2048;
      glds16(ksrc,        kl);
      glds16(ksrc + 512,  kl + 512);
      glds16(ksrc + 1024, kl + 1024);
      glds16(ksrc + 1536, kl + 1536);
      const u16* vsrc = vbb + (long)(w*32 + (lane >> 3))*VROW + n1 + (lane & 7)*8;
      u16* vl = ktn + w*2048;
      glds16(vsrc,            vl);
      glds16(vsrc + 8*VROW,   vl + 512);
      glds16(vsrc + 16*VROW,  vl + 1024);
      glds16(vsrc + 24*VROW,  vl + 1536);
    }

    // ---- QK^T (this wave's 32-column half) on buf[cur] ----
    f32x4 sc[2];
    sc[0] = zero4; sc[1] = zero4;
    __builtin_amdgcn_s_setprio(1);
    #pragma unroll
    for (int ks = 0; ks < 8; ks++){
      #pragma unroll
      for (int ns = 0; ns < 2; ns++){
        int n_l = (wn*2 + ns)*16 + l15;
        u16x8 bfrag = *(const u16x8*)&kpc[n_l*256 + (((ks*4 + qd)) ^ ((n_l & 7)*4))*8];
        sc[ns] = mfma16(afrag[ks], bfrag, sc[ns]);
      }
    }
    __builtin_amdgcn_s_setprio(0);

    // ---- mask bias + online softmax (wave-local, own half) ----
    float sEff[2][4];
    #pragma unroll
    for (int ns = 0; ns < 2; ns++){
      int n = n0 + (wn*2 + ns)*16 + l15;
      bool inv = (n >= CNQ);
      bool isEx = (n == CHW);
      int cm = 0;
      if (!inv && !isEx) cm = maskb[n];
      #pragma unroll
      for (int r = 0; r < 4; r++){
        float s = sc[ns][r];
        float se;
        if (inv)        se = -1e30f;
        else if (isEx)  se = s;
        else            se = (rowAllowed[r] & cm) ? s : s - 1e9f;
        sEff[ns][r] = se;
      }
    }
    float al[4], nm[4];
    #pragma unroll
    for (int r = 0; r < 4; r++){
      float tm = red16_max(fmaxf(sEff[0][r], sEff[1][r]));
      float newm = fmaxf(mi[r], tm);
      al[r] = (mi[r] < -1e29f) ? 0.f : __expf(fmaxf(mi[r] - newm, -88.f));
      nm[r] = newm; mi[r] = newm;
    }
    #pragma unroll
    for (int r = 0; r < 4; r++){
      float rs = 0.f;
      int prow = wm*16 + qd*4 + r;
      #pragma unroll
      for (int ns = 0; ns < 2; ns++){
        float p = __expf(fmaxf(sEff[ns][r] - nm[r], -88.f));
        rs += p;
        int ccol = (wn*2 + ns)*16 + l15;
        p_tile[prow*64 + ((ccol >> 3) ^ (prow & 7))*8 + (ccol & 7)] = f2b(p);
      }
      li[r] = li[r]*al[r] + red16_sum(rs);
    }
    // P writes/reads are wave-private regions: no barrier, just drain LDS.
    asm volatile("s_waitcnt lgkmcnt(0)" ::: "memory");

    // ---- rescale T only when the running max actually moved (al!=1) ----
    int needre = (al[0] != 1.f) | (al[1] != 1.f) | (al[2] != 1.f) | (al[3] != 1.f);
    if (__any(needre)){
      #pragma unroll
      for (int ds = 0; ds < 16; ds++){
        #pragma unroll
        for (int r = 0; r < 4; r++) O[ds][r] *= al[r];
      }
    }
    // ---- T += P·Vtile over this wave's 32-column half ----
    {
      int prow2 = wm*16 + l15;
      u16x8 pf = *(const u16x8*)&p_tile[prow2*64 + (((wn*4 + qd)) ^ (prow2 & 7))*8];
      __builtin_amdgcn_s_setprio(1);
      #pragma unroll
      for (int ds = 0; ds < 16; ds++){
        int c = ds*16 + l15;
        u16x8 vf = *(const u16x8*)&ktc[c*64 + (((wn*4 + qd)) ^ (c & 7))*8];
        O[ds] = mfma16(pf, vf, O[ds]);
      }
      __builtin_amdgcn_s_setprio(0);
    }
    __syncthreads();   // buf[cur] reads done; drains vmcnt -> buf[cur^1] ready
  }

  // ---- merge the two N-halves (flash-decoding in-block merge) ----
  if (l15 == 0){
    #pragma unroll
    for (int r = 0; r < 4; r++){
      mlx[(((wm*2 + wn)*16) + qd*4 + r)*2 + 0] = mi[r];
      mlx[(((wm*2 + wn)*16) + qd*4 + r)*2 + 1] = li[r];
    }
  }
  __syncthreads();
  float alpha[4], linv[4];
  #pragma unroll
  for (int r = 0; r < 4; r++){
    float mo = mlx[(((wm*2 + (1 - wn))*16) + qd*4 + r)*2 + 0];
    float lo = mlx[(((wm*2 + (1 - wn))*16) + qd*4 + r)*2 + 1];
    float ms = fmaxf(mi[r], mo);
    float aS = (mi[r] < -1e29f) ? 0.f : __expf(mi[r] - ms);
    float aO = (mo    < -1e29f) ? 0.f : __expf(mo - ms);
    float ls = li[r]*aS + lo*aO;
    alpha[r] = aS;
    linv[r] = (ls > 0.f) ? (1.0f / ls) : 0.f;
  }
  float* Tsum = (float*)smem;         // 64KB f32 scratch spanning kp0+kt0
  if (wn == 1){
    #pragma unroll
    for (int ds = 0; ds < 16; ds++){
      #pragma unroll
      for (int r = 0; r < 4; r++)
        Tsum[(wm*16 + qd*4 + r)*256 + ds*16 + l15] = O[ds][r]*alpha[r];
    }
  }
  __syncthreads();
  if (wn == 0){
    #pragma unroll
    for (int ds = 0; ds < 16; ds++){
      #pragma unroll
      for (int r = 0; r < 4; r++)
        O[ds][r] = (O[ds][r]*alpha[r] + Tsum[(wm*16 + qd*4 + r)*256 + ds*16 + l15]) * linv[r];
    }
  }
  __syncthreads();                    // Tsum reads done before bf16 overwrite
  if (wn == 0){
    #pragma unroll
    for (int ds = 0; ds < 16; ds++){
      #pragma unroll
      for (int r = 0; r < 4; r++){
        int prow = wm*16 + qd*4 + r;
        int ccol = ds*16 + l15;
        kp0[prow*256 + ((ccol >> 3) ^ ((prow & 7)*4))*8 + (ccol & 7)] = f2b(O[ds][r]);
      }
    }
  }
  __syncthreads();
  u16x8 tfrag[8];
  {
    int arl = wm*16 + l15;
    #pragma unroll
    for (int ks = 0; ks < 8; ks++)
      tfrag[ks] = *(const u16x8*)&kp0[arl*256 + (((ks*4 + qd)) ^ ((arl & 7)*4))*8];
  }
  // ---- final projection F = T_norm · Wv^T, ds split between halves ----
  f32x4 F[8];
  #pragma unroll
  for (int i = 0; i < 8; i++) F[i] = zero4;
  #pragma unroll
  for (int ks = 0; ks < 8; ks++){
    #pragma unroll
    for (int ds = 0; ds < 8; ds++){
      int dsg = wn*8 + ds;
      const float* wr = Wv + (long)(dsg*16 + l15)*CC + ks*32 + qd*8;
      f32x4 w0 = *(const f32x4*)wr;
      f32x4 w1 = *(const f32x4*)(wr + 4);
      F[ds] = mfma16(tfrag[ks], cvt8(w0, w1), F[ds]);
    }
  }

  // ---- epilogue: f32 img_out only (query rows gathered later by gather_k) ---
  float* oi = out_img + (long)b*257*CHW;
  const float* fi = imgf + (long)b*CC*CHW;
  int mb = m0 + wm*16 + qd*4;
  #pragma unroll
  for (int ds = 0; ds < 8; ds++){
    int d = (wn*8 + ds)*16 + l15;
    f32x4 ivals = *(const f32x4*)(fi + (long)d*CHW + mb);
    f32x4 ovals;
    #pragma unroll
    for (int r = 0; r < 4; r++) ovals[r] = F[ds][r] + ivals[r];
    *(f32x4*)(oi + (long)d*CHW + mb) = ovals;
  }
}

// ---------------- K4b: compact query rows (column gather done ONCE) ----------
// 600 blocks: one (b,q) each; 257 scattered line-touches per row instead of
// qhead1's 4x-redundant per-block gather (79MB -> 20MB of L2 gather traffic).
__global__ __launch_bounds__(256) void gather_k(const float* __restrict__ out_img,
    const int* __restrict__ qids, float* __restrict__ qg){
  int id = blockIdx.x;
  int b = id / NQP, q = id - b*NQP;
  int m = qids[b*160 + q];
  int t = threadIdx.x;
  const float* oib = out_img + (long)b*257*CHW + m;
  qg[(long)id*257 + t] = oib[(long)t*CHW];
  if (t == 0) qg[(long)id*257 + 256] = oib[(long)256*CHW];
}

// ---------------- K5a: LN + layer1 chunk (broadcast GEMV, coalesced) ---------
__global__ __launch_bounds__(256) void qhead1_k(const float* __restrict__ qg,
    const float* __restrict__ g, const float* __restrict__ be,
    const float* __restrict__ W1t, const float* __restrict__ b1,
    float* __restrict__ Hb){
  int hc = blockIdx.x, rb = blockIdx.y;
  int t = threadIdx.x, lane = t & 63, wv = t >> 6;
  __shared__ __align__(16) float xl[4][260];
  // ---- LN: wave wv normalizes row rb*4+wv (coalesced reads from qg) ----
  {
    const float* row = qg + (long)(rb*4 + wv)*257;
    float v[4];
    #pragma unroll
    for (int j = 0; j < 4; j++) v[j] = row[lane + j*64];
    float v4 = (lane == 0) ? row[256] : 0.f;
    float s = v[0]+v[1]+v[2]+v[3]+v4;
    #pragma unroll
    for (int d = 1; d < 64; d <<= 1) s += __shfl_xor(s, d, 64);
    float mu = s / 257.f;
    float d4 = (lane == 0) ? (v4 - mu) : 0.f;
    float vs = d4*d4;
    #pragma unroll
    for (int j = 0; j < 4; j++){ float dd = v[j]-mu; vs += dd*dd; }
    #pragma unroll
    for (int d = 1; d < 64; d <<= 1) vs += __shfl_xor(vs, d, 64);
    float inv = 1.0f / sqrtf(vs/257.f + 1e-5f);
    #pragma unroll
    for (int j = 0; j < 4; j++)
      xl[wv][lane + j*64] = (v[j]-mu)*inv*g[lane + j*64] + be[lane + j*64];
    if (lane == 0) xl[wv][256] = d4*inv*g[256] + be[256];
  }
  __syncthreads();
  int h = hc*256 + t;
  float acc0=0.f, acc1=0.f, acc2=0.f, acc3=0.f;
  #pragma unroll 8
  for (int c = 0; c < 256; c++){
    float wv_ = W1t[(long)c*CHID + h];
    acc0 += wv_*xl[0][c]; acc1 += wv_*xl[1][c];
    acc2 += wv_*xl[2][c]; acc3 += wv_*xl[3][c];
  }
  {
    float wv_ = W1t[(long)256*CHID + h];
    acc0 += wv_*xl[0][256]; acc1 += wv_*xl[1][256];
    acc2 += wv_*xl[2][256]; acc3 += wv_*xl[3][256];
  }
  float bb = b1[h];
  float* hb = Hb + (long)rb*4*CHID + h;
  hb[0]       = fmaxf(acc0 + bb, 0.f);
  hb[CHID]    = fmaxf(acc1 + bb, 0.f);
  hb[2*CHID]  = fmaxf(acc2 + bb, 0.f);
  hb[3*CHID]  = fmaxf(acc3 + bb, 0.f);
}

// ---------------- K5b: layer2 (broadcast GEMV, coalesced W2t) ----------------
__global__ __launch_bounds__(256) void qhead2_k(float* __restrict__ qbuf,
    const float* __restrict__ Hb, const float* __restrict__ W2t,
    const float* __restrict__ b2){
  int rb = blockIdx.x;
  int t = threadIdx.x, lane = t & 63, wv = t >> 6;
  __shared__ __align__(16) float hl[4][CHID];
  const float* hs = Hb + (long)rb*4*CHID;
  #pragma unroll
  for (int q = 0; q < 4; q++)
    *(f32x4*)&hl[q][t*4] = *(const f32x4*)&hs[(long)q*CHID + t*4];
  __syncthreads();
  float a0=0.f, a1=0.f, a2=0.f, a3=0.f;
  #pragma unroll 8
  for (int c = 0; c < CHID; c++){
    float wv_ = W2t[(long)c*257 + t];
    a0 += wv_*hl[0][c]; a1 += wv_*hl[1][c];
    a2 += wv_*hl[2][c]; a3 += wv_*hl[3][c];
  }
  float bb = b2[t];
  qbuf[(long)(rb*4 + 0)*257 + t] = a0 + bb;
  qbuf[(long)(rb*4 + 1)*257 + t] = a1 + bb;
  qbuf[(long)(rb*4 + 2)*257 + t] = a2 + bb;
  qbuf[(long)(rb*4 + 3)*257 + t] = a3 + bb;
  // ---- o = 256 handled by wave 0: 16 c's per lane, shuffle reduce ----
  if (wv == 0){
    float p0=0.f, p1=0.f, p2=0.f, p3=0.f;
    #pragma unroll
    for (int k = 0; k < 16; k++){
      int c = lane*16 + k;
      float wv_ = W2t[(long)c*257 + 256];
      p0 += wv_*hl[0][c]; p1 += wv_*hl[1][c];
      p2 += wv_*hl[2][c]; p3 += wv_*hl[3][c];
    }
    #pragma unroll
    for (int d = 1; d < 64; d <<= 1){
      p0 += __shfl_xor(p0, d, 64); p1 += __shfl_xor(p1, d, 64);
      p2 += __shfl_xor(p2, d, 64); p3 += __shfl_xor(p3, d, 64);
    }
    if (lane == 0){
      float b256 = b2[256];
      qbuf[(long)(rb*4 + 0)*257 + 256] = p0 + b256;
      qbuf[(long)(rb*4 + 1)*257 + 256] = p1 + b256;
      qbuf[(long)(rb*4 + 2)*257 + 256] = p2 + b256;
      qbuf[(long)(rb*4 + 3)*257 + 256] = p3 + b256;
    }
  }
}

// ---------------- launch: input mapping by SIZE (robust to ordering) ---------
extern "C" void kernel_launch(void* const* d_in, const int* in_sizes, int n_in,
                              void* d_out, int out_size, void* d_ws, size_t ws_size,
                              hipStream_t stream){
  (void)out_size; (void)ws_size;
  int idxImg=-1, idxExe=-1, idxMask=-1, idxB1=-1;
  int idx65[2]={-1,-1}; int n65=0;
  int idx263[2]={-1,-1}; int n263=0;
  int idx257[3]={-1,-1,-1}; int n257=0;
  for (int i = 0; i < n_in; i++){
    int s = in_sizes[i];
    if      (s == 4194304) idxImg = i;
    else if (s == 50176)   idxExe = i;
    else if (s == 16384)   idxMask = i;
    else if (s == 1024)    idxB1 = i;
    else if (s == 65536)  { if (n65 < 2)  idx65[n65++] = i; }
    else if (s == 263168) { if (n263 < 2) idx263[n263++] = i; }
    else if (s == 257)    { if (n257 < 3) idx257[n257++] = i; }
  }
  const float* img  = (const float*)d_in[idxImg];
  const float* exe  = (const float*)d_in[idxExe];
  const float* mask = (const float*)d_in[idxMask];
  const float* S    = (const float*)d_in[idx65[0]];   // S before Wv in both dict & sorted order
  const float* Wv   = (const float*)d_in[idx65[1]];
  const float* W1   = (const float*)d_in[idx263[0]];  // W1 before W2 in both orders
  const float* W2   = (const float*)d_in[idx263[1]];
  const float* b1   = (const float*)d_in[idxB1];
  const float *lng, *lnb, *b2;
  if (idxImg == 0){           // dict order: ln_g, ln_b, b2
    lng = (const float*)d_in[idx257[0]];
    lnb = (const float*)d_in[idx257[1]];
    b2  = (const float*)d_in[idx257[2]];
  } else {                    // name-sorted: b2, ln_b, ln_g
    b2  = (const float*)d_in[idx257[0]];
    lnb = (const float*)d_in[idx257[1]];
    lng = (const float*)d_in[idx257[2]];
  }

  char* ws = (char*)d_ws;
  u16*   Xt   = (u16*)(ws + XT_OFF);
  u16*   Vb   = (u16*)(ws + VB_OFF);
  u16*   St   = (u16*)(ws + ST_OFF);
  float* exeF = (float*)(ws + EXE_OFF);
  float* zl   = (float*)(ws + ZL_OFF);
  float* heat = (float*)(ws + HEAT_OFF);
  int*   qids = (int*)(ws + QID_OFF);
  float* W1t  = (float*)(ws + W1T_OFF);
  float* W2t  = (float*)(ws + W2T_OFF);
  float* Hb   = (float*)(ws + HB_OFF);
  float* qg   = (float*)(ws + QG_OFF);

  float* out      = (float*)d_out;                       // f32 outputs
  float* out_img  = out;                                 // [4][257][4096]
  float* qbuf     = out + (size_t)CB*257*CHW;            // [4][150][257]
  float* out_crd  = qbuf + (size_t)CB*NQP*257;           // [4][150][2]

  prep_k<<<dim3(596), dim3(256), 0, stream>>>(
      exe, S, W1, W2, exeF, zl, Xt, St, W1t, W2t);
  big_k<<<dim3(2112), dim3(256), 0, stream>>>(
      img, exeF, zl, Xt, Vb, heat, out_img);
  topk_k<<<dim3(CB), dim3(1024), 0, stream>>>(heat, qids, out_crd);
  flash_k<<<dim3(64, CB), dim3(512), 0, stream>>>(
      Xt, St, Vb, img, mask, Wv, out_img);
  gather_k<<<dim3(CB*NQP), dim3(256), 0, stream>>>(out_img, qids, qg);
  qhead1_k<<<dim3(4, CB*NQP/4), dim3(256), 0, stream>>>(
      qg, lng, lnb, W1t, b1, Hb);
  qhead2_k<<<dim3(CB*NQP/4), dim3(256), 0, stream>>>(qbuf, Hb, W2t, b2);
}